// Round 1
// baseline (1898.698 us; speedup 1.0000x reference)
//
#include <hip/hip_runtime.h>

// H2GCN forward: embed GEMM -> [spmm(e1)|spmm(e2)] + BN  x2 -> spmm concat -> head GEMM
// Strategy: build CSR (hist/scan/scatter) in workspace each call; pull-SPMM wave-per-row.

#define NN  50000
#define E1N 800000
#define E2N 1600000

// ---------------- setup kernels ----------------

__global__ __launch_bounds__(256) void zero_kernel(int* a, int na, int* b, int nb, float* c, int nc) {
    int i = blockIdx.x * 256 + threadIdx.x;
    if (i < na) a[i] = 0;
    if (i < nb) b[i] = 0;
    if (i < nc) c[i] = 0.f;
}

__global__ __launch_bounds__(256) void hist_kernel(const int* __restrict__ r1, const int* __restrict__ r2,
                                                   int* h1, int* h2) {
    int i = blockIdx.x * 256 + threadIdx.x;
    if (i < E1N) atomicAdd(&h1[r1[i]], 1);
    else if (i < E1N + E2N) atomicAdd(&h2[r2[i - E1N]], 1);
}

// blockIdx.x = 0 -> graph1, 1 -> graph2. hist array doubles as cursor output.
__global__ __launch_bounds__(1024) void scan_kernel(int* hist1, int* rp1, int* hist2, int* rp2) {
    int* hist = blockIdx.x ? hist2 : hist1;
    int* rp   = blockIdx.x ? rp2   : rp1;
    const int t = threadIdx.x;
    const int CH = 49;                       // 1024*49 >= 50000
    int base = t * CH;
    int lim = NN - base; if (lim > CH) lim = CH; if (lim < 0) lim = 0;
    int lsum = 0;
    for (int j = 0; j < lim; j++) lsum += hist[base + j];
    __shared__ int s[1024];
    s[t] = lsum;
    __syncthreads();
    for (int off = 1; off < 1024; off <<= 1) {
        int v = (t >= off) ? s[t - off] : 0;
        __syncthreads();
        s[t] += v;
        __syncthreads();
    }
    int run = s[t] - lsum;                   // exclusive prefix
    for (int j = 0; j < lim; j++) {
        int hv = hist[base + j];             // read before overwrite (alias: cursor)
        rp[base + j]   = run;
        hist[base + j] = run;                // cursor init
        run += hv;
    }
    if (t == 0) rp[NN] = s[1023];
}

__global__ __launch_bounds__(256) void scatter_kernel(
        const int* __restrict__ r1, const int* __restrict__ c1, const float* __restrict__ v1,
        const int* __restrict__ r2, const int* __restrict__ c2, const float* __restrict__ v2,
        int* cur1, int* cs1, float* vs1, int* cur2, int* cs2, float* vs2) {
    int i = blockIdx.x * 256 + threadIdx.x;
    if (i < E1N) {
        int r = r1[i];
        int idx = atomicAdd(&cur1[r], 1);
        cs1[idx] = c1[i]; vs1[idx] = v1[i];
    } else if (i < E1N + E2N) {
        int k = i - E1N;
        int r = r2[k];
        int idx = atomicAdd(&cur2[r], 1);
        cs2[idx] = c2[k]; vs2[idx] = v2[k];
    }
}

// ---------------- dense embed: h = relu(x @ W_embed + b) ----------------
// block 256 = 4 nodes x 64 cols
__global__ __launch_bounds__(256) void embed_kernel(const float* __restrict__ x, const float* __restrict__ W,
                                                    const float* __restrict__ b, float* __restrict__ h) {
    int col  = threadIdx.x & 63;
    int node = blockIdx.x * 4 + (threadIdx.x >> 6);
    if (node >= NN) return;
    const float* xr = x + (size_t)node * 256;
    float acc = 0.f;
    #pragma unroll 4
    for (int k = 0; k < 256; k += 4) {
        float4 xv = *(const float4*)(xr + k);
        acc = fmaf(xv.x, W[(k + 0) * 64 + col], acc);
        acc = fmaf(xv.y, W[(k + 1) * 64 + col], acc);
        acc = fmaf(xv.z, W[(k + 2) * 64 + col], acc);
        acc = fmaf(xv.w, W[(k + 3) * 64 + col], acc);
    }
    acc += b[col];
    h[(size_t)node * 64 + col] = fmaxf(acc, 0.f);
}

// ---------------- pull SPMM: dst[row, off + f] = sum_edges val * src[col, f] ----------------
// wave-per-row, lane owns VEC consecutive features (srcF = 64*VEC)
template <int VEC>
__global__ __launch_bounds__(256) void spmm_kernel(const int* __restrict__ rp, const int* __restrict__ cs,
                                                   const float* __restrict__ vs, const float* __restrict__ src,
                                                   float* __restrict__ dst, int dstLD, int dstOff) {
    int lane = threadIdx.x & 63;
    int row  = blockIdx.x * 4 + (threadIdx.x >> 6);
    if (row >= NN) return;
    int beg = rp[row], end = rp[row + 1];
    float acc[VEC];
    #pragma unroll
    for (int u = 0; u < VEC; u++) acc[u] = 0.f;
    const int srcF = 64 * VEC;
    for (int j = beg; j < end; j++) {
        int   c = cs[j];
        float v = vs[j];
        const float* sp = src + (size_t)c * srcF + lane * VEC;
        if (VEC == 4) {
            float4 s4 = *(const float4*)sp;
            acc[0] = fmaf(v, s4.x, acc[0]); acc[1] = fmaf(v, s4.y, acc[1]);
            acc[2] = fmaf(v, s4.z, acc[2]); acc[3] = fmaf(v, s4.w, acc[3]);
        } else if (VEC == 2) {
            float2 s2 = *(const float2*)sp;
            acc[0] = fmaf(v, s2.x, acc[0]); acc[1] = fmaf(v, s2.y, acc[1]);
        } else {
            acc[0] = fmaf(v, sp[0], acc[0]);
        }
    }
    float* dp = dst + (size_t)row * dstLD + dstOff + lane * VEC;
    if (VEC == 4)      *(float4*)dp = make_float4(acc[0], acc[1], acc[2], acc[3]);
    else if (VEC == 2) *(float2*)dp = make_float2(acc[0], acc[1]);
    else               dp[0] = acc[0];
}

// ---------------- BN stats / finalize / apply ----------------
template <int F>
__global__ __launch_bounds__(256) void bn_stats_kernel(const float* __restrict__ c, float* sum, float* sumsq) {
    constexpr int SL = 256 / F;              // slices per block (F=128 -> 2, F=256 -> 1)
    int f  = threadIdx.x % F;
    int sl = threadIdx.x / F;
    float s = 0.f, ss = 0.f;
    for (int r = blockIdx.x * SL + sl; r < NN; r += gridDim.x * SL) {
        float v = c[(size_t)r * F + f];
        s += v; ss += v * v;
    }
    __shared__ float ls[256], lss[256];
    ls[threadIdx.x] = s; lss[threadIdx.x] = ss;
    __syncthreads();
    if (sl == 0) {
        #pragma unroll
        for (int u = 1; u < SL; u++) { s += ls[f + u * F]; ss += lss[f + u * F]; }
        atomicAdd(&sum[f], s);
        atomicAdd(&sumsq[f], ss);
    }
}

__global__ void bn_finalize_kernel(const float* sum, const float* sumsq, const float* __restrict__ gamma,
                                   const float* __restrict__ beta, float* scale, float* shift, int F) {
    int f = blockIdx.x * blockDim.x + threadIdx.x;
    if (f >= F) return;
    float m   = sum[f] * (1.0f / NN);
    float var = sumsq[f] * (1.0f / NN) - m * m;
    float sc  = gamma[f] * rsqrtf(var + 1e-5f);
    scale[f] = sc;
    shift[f] = beta[f] - m * sc;
}

template <int F>
__global__ __launch_bounds__(256) void bn_apply_kernel(float* __restrict__ c, const float* __restrict__ scale,
                                                       const float* __restrict__ shift) {
    size_t i = ((size_t)blockIdx.x * 256 + threadIdx.x) * 4;
    if (i >= (size_t)NN * F) return;
    int f = (int)(i & (F - 1));
    float4 v  = *(float4*)(c + i);
    float4 sc = *(const float4*)(scale + f);
    float4 sh = *(const float4*)(shift + f);
    v.x = fmaf(v.x, sc.x, sh.x);
    v.y = fmaf(v.y, sc.y, sh.y);
    v.z = fmaf(v.z, sc.z, sh.z);
    v.w = fmaf(v.w, sc.w, sh.w);
    *(float4*)(c + i) = v;
}

// ---------------- head GEMM: out = [h|c0|c1|c2] @ W_head + b ----------------
__device__ __forceinline__ float dot_seg(const float* __restrict__ v, int len,
                                         const float* __restrict__ W, int col) {
    float acc = 0.f;
    #pragma unroll 4
    for (int k = 0; k < len; k += 4) {
        float4 x = *(const float4*)(v + k);
        acc = fmaf(x.x, W[(k + 0) * 32 + col], acc);
        acc = fmaf(x.y, W[(k + 1) * 32 + col], acc);
        acc = fmaf(x.z, W[(k + 2) * 32 + col], acc);
        acc = fmaf(x.w, W[(k + 3) * 32 + col], acc);
    }
    return acc;
}

__global__ __launch_bounds__(256) void head_kernel(const float* __restrict__ h, const float* __restrict__ c0,
                                                   const float* __restrict__ c1, const float* __restrict__ c2,
                                                   const float* __restrict__ W, const float* __restrict__ b,
                                                   float* __restrict__ out) {
    int col  = threadIdx.x & 31;
    int node = blockIdx.x * 8 + (threadIdx.x >> 5);
    if (node >= NN) return;
    float acc = b[col];
    acc += dot_seg(h  + (size_t)node * 64,  64,  W + 0   * 32, col);
    acc += dot_seg(c0 + (size_t)node * 128, 128, W + 64  * 32, col);
    acc += dot_seg(c1 + (size_t)node * 256, 256, W + 192 * 32, col);
    acc += dot_seg(c2 + (size_t)node * 512, 512, W + 448 * 32, col);
    out[(size_t)node * 32 + col] = acc;
}

// ---------------- launch ----------------

extern "C" void kernel_launch(void* const* d_in, const int* in_sizes, int n_in,
                              void* d_out, int out_size, void* d_ws, size_t ws_size,
                              hipStream_t stream) {
    const float* x      = (const float*)d_in[0];
    const int*   e1_row = (const int*)d_in[1];
    const int*   e1_col = (const int*)d_in[2];
    const float* e1_val = (const float*)d_in[3];
    const int*   e2_row = (const int*)d_in[4];
    const int*   e2_col = (const int*)d_in[5];
    const float* e2_val = (const float*)d_in[6];
    const float* W_emb  = (const float*)d_in[7];
    const float* b_emb  = (const float*)d_in[8];
    const float* bn0_g  = (const float*)d_in[9];
    const float* bn0_b  = (const float*)d_in[10];
    const float* bn1_g  = (const float*)d_in[11];
    const float* bn1_b  = (const float*)d_in[12];
    const float* W_head = (const float*)d_in[13];
    const float* b_head = (const float*)d_in[14];
    float* out = (float*)d_out;

    char* ws = (char*)d_ws;
    auto alloc = [&](size_t bytes) -> char* {
        char* p = ws;
        ws += (bytes + 255) & ~(size_t)255;
        return p;
    };
    int*   rp1   = (int*)alloc((NN + 1) * 4);
    int*   cur1  = (int*)alloc(NN * 4);          // hist -> cursor
    int*   rp2   = (int*)alloc((NN + 1) * 4);
    int*   cur2  = (int*)alloc(NN * 4);
    int*   cs1   = (int*)alloc(E1N * 4);
    float* vs1   = (float*)alloc(E1N * 4);
    int*   cs2   = (int*)alloc(E2N * 4);
    float* vs2   = (float*)alloc(E2N * 4);
    float* stats = (float*)alloc(1536 * 4);
    float* h     = (float*)alloc((size_t)NN * 64 * 4);
    float* c0    = (float*)alloc((size_t)NN * 128 * 4);
    float* c1    = (float*)alloc((size_t)NN * 256 * 4);
    float* c2    = (float*)alloc((size_t)NN * 512 * 4);

    float* sum0   = stats;        float* sq0    = stats + 128;
    float* sum1   = stats + 256;  float* sq1    = stats + 512;
    float* scale0 = stats + 768;  float* shift0 = stats + 896;
    float* scale1 = stats + 1024; float* shift1 = stats + 1280;

    const int EB = (E1N + E2N + 255) / 256;      // 9375
    const int RB = (NN + 3) / 4;                 // 12500

    // CSR build
    zero_kernel<<<(NN + 255) / 256, 256, 0, stream>>>(cur1, NN, cur2, NN, stats, 768);
    hist_kernel<<<EB, 256, 0, stream>>>(e1_row, e2_row, cur1, cur2);
    scan_kernel<<<2, 1024, 0, stream>>>(cur1, rp1, cur2, rp2);
    scatter_kernel<<<EB, 256, 0, stream>>>(e1_row, e1_col, e1_val, e2_row, e2_col, e2_val,
                                           cur1, cs1, vs1, cur2, cs2, vs2);

    // embed
    embed_kernel<<<RB, 256, 0, stream>>>(x, W_emb, b_emb, h);

    // conv0 -> c0 (raw), then BN
    spmm_kernel<1><<<RB, 256, 0, stream>>>(rp1, cs1, vs1, h, c0, 128, 0);
    spmm_kernel<1><<<RB, 256, 0, stream>>>(rp2, cs2, vs2, h, c0, 128, 64);
    bn_stats_kernel<128><<<256, 256, 0, stream>>>(c0, sum0, sq0);
    bn_finalize_kernel<<<1, 128, 0, stream>>>(sum0, sq0, bn0_g, bn0_b, scale0, shift0, 128);
    bn_apply_kernel<128><<<(NN * 128 / 4 + 255) / 256, 256, 0, stream>>>(c0, scale0, shift0);

    // conv1 -> c1 (raw), then BN
    spmm_kernel<2><<<RB, 256, 0, stream>>>(rp1, cs1, vs1, c0, c1, 256, 0);
    spmm_kernel<2><<<RB, 256, 0, stream>>>(rp2, cs2, vs2, c0, c1, 256, 128);
    bn_stats_kernel<256><<<256, 256, 0, stream>>>(c1, sum1, sq1);
    bn_finalize_kernel<<<1, 256, 0, stream>>>(sum1, sq1, bn1_g, bn1_b, scale1, shift1, 256);
    bn_apply_kernel<256><<<(NN * 256 / 4 + 255) / 256, 256, 0, stream>>>(c1, scale1, shift1);

    // conv2 -> c2 (no BN)
    spmm_kernel<4><<<RB, 256, 0, stream>>>(rp1, cs1, vs1, c1, c2, 512, 0);
    spmm_kernel<4><<<RB, 256, 0, stream>>>(rp2, cs2, vs2, c1, c2, 512, 256);

    // head
    head_kernel<<<(NN + 7) / 8, 256, 0, stream>>>(h, c0, c1, c2, W_head, b_head, out);
}

// Round 2
// 1580.291 us; speedup vs baseline: 1.2015x; 1.2015x over previous
//
#include <hip/hip_runtime.h>

// H2GCN forward. All activations live in one fused J[N, 960] buffer:
//   cols [0,64)=h  [64,192)=c0  [192,448)=c1  [448,960)=c2
// CSR built in-workspace each call (hist/scan/scatter). Pull-SPMM wave-per-row
// with 4-edge unrolled gather for memory ILP. Head GEMM: 4 cols/thread, 4 acc chains.

#define NN  50000
#define E1N 800000
#define E2N 1600000
#define LD  960          // J leading dimension (floats)
#define RB  12500        // (NN+3)/4 row-blocks for spmm

// ---------------- setup kernels ----------------

__global__ __launch_bounds__(256) void zero_kernel(int* a, int na, int* b, int nb, float* c, int nc) {
    int i = blockIdx.x * 256 + threadIdx.x;
    if (i < na) a[i] = 0;
    if (i < nb) b[i] = 0;
    if (i < nc) c[i] = 0.f;
}

__global__ __launch_bounds__(256) void hist_kernel(const int* __restrict__ r1, const int* __restrict__ r2,
                                                   int* h1, int* h2) {
    int i = blockIdx.x * 256 + threadIdx.x;
    if (i < E1N) atomicAdd(&h1[r1[i]], 1);
    else if (i < E1N + E2N) atomicAdd(&h2[r2[i - E1N]], 1);
}

__global__ __launch_bounds__(1024) void scan_kernel(int* hist1, int* rp1, int* hist2, int* rp2) {
    int* hist = blockIdx.x ? hist2 : hist1;
    int* rp   = blockIdx.x ? rp2   : rp1;
    const int t = threadIdx.x;
    const int CH = 49;                       // 1024*49 >= 50000
    int base = t * CH;
    int lim = NN - base; if (lim > CH) lim = CH; if (lim < 0) lim = 0;
    int lsum = 0;
    for (int j = 0; j < lim; j++) lsum += hist[base + j];
    __shared__ int s[1024];
    s[t] = lsum;
    __syncthreads();
    for (int off = 1; off < 1024; off <<= 1) {
        int v = (t >= off) ? s[t - off] : 0;
        __syncthreads();
        s[t] += v;
        __syncthreads();
    }
    int run = s[t] - lsum;                   // exclusive prefix
    for (int j = 0; j < lim; j++) {
        int hv = hist[base + j];             // read before overwrite (alias: cursor)
        rp[base + j]   = run;
        hist[base + j] = run;                // cursor init
        run += hv;
    }
    if (t == 0) rp[NN] = s[1023];
}

__global__ __launch_bounds__(256) void scatter_kernel(
        const int* __restrict__ r1, const int* __restrict__ c1, const float* __restrict__ v1,
        const int* __restrict__ r2, const int* __restrict__ c2, const float* __restrict__ v2,
        int* cur1, int* cs1, float* vs1, int* cur2, int* cs2, float* vs2) {
    int i = blockIdx.x * 256 + threadIdx.x;
    if (i < E1N) {
        int r = r1[i];
        int idx = atomicAdd(&cur1[r], 1);
        cs1[idx] = c1[i]; vs1[idx] = v1[i];
    } else if (i < E1N + E2N) {
        int k = i - E1N;
        int r = r2[k];
        int idx = atomicAdd(&cur2[r], 1);
        cs2[idx] = c2[k]; vs2[idx] = v2[k];
    }
}

// ---------------- dense embed: J[:,0:64] = relu(x @ W_embed + b) ----------------
__global__ __launch_bounds__(256) void embed_kernel(const float* __restrict__ x, const float* __restrict__ W,
                                                    const float* __restrict__ b, float* __restrict__ J) {
    int col  = threadIdx.x & 63;
    int node = blockIdx.x * 4 + (threadIdx.x >> 6);
    if (node >= NN) return;
    const float* xr = x + (size_t)node * 256;
    float acc = 0.f;
    #pragma unroll 4
    for (int k = 0; k < 256; k += 4) {
        float4 xv = *(const float4*)(xr + k);
        acc = fmaf(xv.x, W[(k + 0) * 64 + col], acc);
        acc = fmaf(xv.y, W[(k + 1) * 64 + col], acc);
        acc = fmaf(xv.z, W[(k + 2) * 64 + col], acc);
        acc = fmaf(xv.w, W[(k + 3) * 64 + col], acc);
    }
    acc += b[col];
    J[(size_t)node * LD + col] = fmaxf(acc, 0.f);
}

// ---------------- pull SPMM (both graphs in one launch) ----------------
// wave-per-row, lane owns VEC consecutive features of a 64*VEC-wide src slice.
// blockIdx.x < RB -> graph1 (dst col colOff), else graph2 (dst col colOff + 64*VEC).
template <int VEC>
__global__ __launch_bounds__(256) void spmm_dual_kernel(
        const int* __restrict__ rp1, const int* __restrict__ cs1, const float* __restrict__ vs1,
        const int* __restrict__ rp2, const int* __restrict__ cs2, const float* __restrict__ vs2,
        const float* __restrict__ src,   // J + srcColOff
        float* __restrict__ dst,         // J
        int colOff) {
    int g    = (blockIdx.x >= RB) ? 1 : 0;
    int bx   = blockIdx.x - g * RB;
    int lane = threadIdx.x & 63;
    int row  = bx * 4 + (threadIdx.x >> 6);
    if (row >= NN) return;
    const int*   rp = g ? rp2 : rp1;
    const int*   cs = g ? cs2 : cs1;
    const float* vs = g ? vs2 : vs1;
    int beg = rp[row], end = rp[row + 1];

    float acc[VEC];
    #pragma unroll
    for (int u = 0; u < VEC; u++) acc[u] = 0.f;
    const float* sbase = src + lane * VEC;
    const int srcF = 64 * VEC;

    int j = beg;
    for (; j + 4 <= end; j += 4) {
        int   cA = cs[j+0], cB = cs[j+1], cC = cs[j+2], cD = cs[j+3];
        float vA = vs[j+0], vB = vs[j+1], vC = vs[j+2], vD = vs[j+3];
        const float* pA = sbase + (size_t)cA * LD;
        const float* pB = sbase + (size_t)cB * LD;
        const float* pC = sbase + (size_t)cC * LD;
        const float* pD = sbase + (size_t)cD * LD;
        if constexpr (VEC == 4) {
            float4 sA = *(const float4*)pA; float4 sB = *(const float4*)pB;
            float4 sC = *(const float4*)pC; float4 sD = *(const float4*)pD;
            acc[0]=fmaf(vA,sA.x,acc[0]); acc[1]=fmaf(vA,sA.y,acc[1]); acc[2]=fmaf(vA,sA.z,acc[2]); acc[3]=fmaf(vA,sA.w,acc[3]);
            acc[0]=fmaf(vB,sB.x,acc[0]); acc[1]=fmaf(vB,sB.y,acc[1]); acc[2]=fmaf(vB,sB.z,acc[2]); acc[3]=fmaf(vB,sB.w,acc[3]);
            acc[0]=fmaf(vC,sC.x,acc[0]); acc[1]=fmaf(vC,sC.y,acc[1]); acc[2]=fmaf(vC,sC.z,acc[2]); acc[3]=fmaf(vC,sC.w,acc[3]);
            acc[0]=fmaf(vD,sD.x,acc[0]); acc[1]=fmaf(vD,sD.y,acc[1]); acc[2]=fmaf(vD,sD.z,acc[2]); acc[3]=fmaf(vD,sD.w,acc[3]);
        } else if constexpr (VEC == 2) {
            float2 sA = *(const float2*)pA; float2 sB = *(const float2*)pB;
            float2 sC = *(const float2*)pC; float2 sD = *(const float2*)pD;
            acc[0]=fmaf(vA,sA.x,acc[0]); acc[1]=fmaf(vA,sA.y,acc[1]);
            acc[0]=fmaf(vB,sB.x,acc[0]); acc[1]=fmaf(vB,sB.y,acc[1]);
            acc[0]=fmaf(vC,sC.x,acc[0]); acc[1]=fmaf(vC,sC.y,acc[1]);
            acc[0]=fmaf(vD,sD.x,acc[0]); acc[1]=fmaf(vD,sD.y,acc[1]);
        } else {
            float sA = *pA, sB = *pB, sC = *pC, sD = *pD;
            acc[0]=fmaf(vA,sA,acc[0]); acc[0]=fmaf(vB,sB,acc[0]);
            acc[0]=fmaf(vC,sC,acc[0]); acc[0]=fmaf(vD,sD,acc[0]);
        }
    }
    for (; j < end; j++) {
        int c = cs[j]; float v = vs[j];
        const float* p = sbase + (size_t)c * LD;
        if constexpr (VEC == 4) {
            float4 s = *(const float4*)p;
            acc[0]=fmaf(v,s.x,acc[0]); acc[1]=fmaf(v,s.y,acc[1]); acc[2]=fmaf(v,s.z,acc[2]); acc[3]=fmaf(v,s.w,acc[3]);
        } else if constexpr (VEC == 2) {
            float2 s = *(const float2*)p;
            acc[0]=fmaf(v,s.x,acc[0]); acc[1]=fmaf(v,s.y,acc[1]);
        } else {
            acc[0] = fmaf(v, *p, acc[0]);
        }
    }

    float* dp = dst + (size_t)row * LD + colOff + g * srcF + lane * VEC;
    if constexpr (VEC == 4)      *(float4*)dp = make_float4(acc[0], acc[1], acc[2], acc[3]);
    else if constexpr (VEC == 2) *(float2*)dp = make_float2(acc[0], acc[1]);
    else                         dp[0] = acc[0];
}

// ---------------- BN stats / finalize / apply (on J column slice) ----------------
template <int F>
__global__ __launch_bounds__(256) void bn_stats_kernel(const float* __restrict__ c, float* sum, float* sumsq) {
    constexpr int SL = 256 / F;              // slices per block
    int f  = threadIdx.x % F;
    int sl = threadIdx.x / F;
    float s = 0.f, ss = 0.f;
    for (int r = blockIdx.x * SL + sl; r < NN; r += gridDim.x * SL) {
        float v = c[(size_t)r * LD + f];
        s += v; ss += v * v;
    }
    __shared__ float ls[256], lss[256];
    ls[threadIdx.x] = s; lss[threadIdx.x] = ss;
    __syncthreads();
    if (sl == 0) {
        #pragma unroll
        for (int u = 1; u < SL; u++) { s += ls[f + u * F]; ss += lss[f + u * F]; }
        atomicAdd(&sum[f], s);
        atomicAdd(&sumsq[f], ss);
    }
}

__global__ void bn_finalize_kernel(const float* sum, const float* sumsq, const float* __restrict__ gamma,
                                   const float* __restrict__ beta, float* scale, float* shift, int F) {
    int f = blockIdx.x * blockDim.x + threadIdx.x;
    if (f >= F) return;
    float m   = sum[f] * (1.0f / NN);
    float var = sumsq[f] * (1.0f / NN) - m * m;
    float sc  = gamma[f] * rsqrtf(var + 1e-5f);
    scale[f] = sc;
    shift[f] = beta[f] - m * sc;
}

template <int F>
__global__ __launch_bounds__(256) void bn_apply_kernel(float* __restrict__ c, const float* __restrict__ scale,
                                                       const float* __restrict__ shift) {
    constexpr int FV = F / 4;                // float4s per node (32 or 64, pow2)
    int idx  = blockIdx.x * 256 + threadIdx.x;
    int node = idx / FV;
    int fo   = (idx % FV) * 4;
    if (node >= NN) return;
    float* p = c + (size_t)node * LD + fo;
    float4 v  = *(float4*)p;
    float4 sc = *(const float4*)(scale + fo);
    float4 sh = *(const float4*)(shift + fo);
    v.x = fmaf(v.x, sc.x, sh.x);
    v.y = fmaf(v.y, sc.y, sh.y);
    v.z = fmaf(v.z, sc.z, sh.z);
    v.w = fmaf(v.w, sc.w, sh.w);
    *(float4*)p = v;
}

// ---------------- head GEMM: out = J @ W_head + b ----------------
// thread = (node, 4-col group); 4 independent acc chains; float4 loads throughout.
__global__ __launch_bounds__(256) void head_kernel(const float* __restrict__ J, const float* __restrict__ W,
                                                   const float* __restrict__ b, float* __restrict__ out) {
    int cg   = (threadIdx.x & 7) * 4;              // col 0,4,...,28
    int node = blockIdx.x * 32 + (threadIdx.x >> 3);
    if (node >= NN) return;
    const float* v = J + (size_t)node * LD;
    float4 acc = make_float4(0.f, 0.f, 0.f, 0.f);
    #pragma unroll 2
    for (int k = 0; k < 960; k += 4) {
        float4 x  = *(const float4*)(v + k);
        float4 w0 = *(const float4*)(W + (k + 0) * 32 + cg);
        float4 w1 = *(const float4*)(W + (k + 1) * 32 + cg);
        float4 w2 = *(const float4*)(W + (k + 2) * 32 + cg);
        float4 w3 = *(const float4*)(W + (k + 3) * 32 + cg);
        acc.x = fmaf(x.x, w0.x, acc.x); acc.y = fmaf(x.x, w0.y, acc.y);
        acc.z = fmaf(x.x, w0.z, acc.z); acc.w = fmaf(x.x, w0.w, acc.w);
        acc.x = fmaf(x.y, w1.x, acc.x); acc.y = fmaf(x.y, w1.y, acc.y);
        acc.z = fmaf(x.y, w1.z, acc.z); acc.w = fmaf(x.y, w1.w, acc.w);
        acc.x = fmaf(x.z, w2.x, acc.x); acc.y = fmaf(x.z, w2.y, acc.y);
        acc.z = fmaf(x.z, w2.z, acc.z); acc.w = fmaf(x.z, w2.w, acc.w);
        acc.x = fmaf(x.w, w3.x, acc.x); acc.y = fmaf(x.w, w3.y, acc.y);
        acc.z = fmaf(x.w, w3.z, acc.z); acc.w = fmaf(x.w, w3.w, acc.w);
    }
    float4 bb = *(const float4*)(b + cg);
    acc.x += bb.x; acc.y += bb.y; acc.z += bb.z; acc.w += bb.w;
    *(float4*)(out + (size_t)node * 32 + cg) = acc;
}

// ---------------- launch ----------------

extern "C" void kernel_launch(void* const* d_in, const int* in_sizes, int n_in,
                              void* d_out, int out_size, void* d_ws, size_t ws_size,
                              hipStream_t stream) {
    const float* x      = (const float*)d_in[0];
    const int*   e1_row = (const int*)d_in[1];
    const int*   e1_col = (const int*)d_in[2];
    const float* e1_val = (const float*)d_in[3];
    const int*   e2_row = (const int*)d_in[4];
    const int*   e2_col = (const int*)d_in[5];
    const float* e2_val = (const float*)d_in[6];
    const float* W_emb  = (const float*)d_in[7];
    const float* b_emb  = (const float*)d_in[8];
    const float* bn0_g  = (const float*)d_in[9];
    const float* bn0_b  = (const float*)d_in[10];
    const float* bn1_g  = (const float*)d_in[11];
    const float* bn1_b  = (const float*)d_in[12];
    const float* W_head = (const float*)d_in[13];
    const float* b_head = (const float*)d_in[14];
    float* out = (float*)d_out;

    char* ws = (char*)d_ws;
    auto alloc = [&](size_t bytes) -> char* {
        char* p = ws;
        ws += (bytes + 255) & ~(size_t)255;
        return p;
    };
    int*   rp1   = (int*)alloc((NN + 1) * 4);
    int*   cur1  = (int*)alloc(NN * 4);
    int*   rp2   = (int*)alloc((NN + 1) * 4);
    int*   cur2  = (int*)alloc(NN * 4);
    int*   cs1   = (int*)alloc(E1N * 4);
    float* vs1   = (float*)alloc(E1N * 4);
    int*   cs2   = (int*)alloc(E2N * 4);
    float* vs2   = (float*)alloc(E2N * 4);
    float* stats = (float*)alloc(1536 * 4);
    float* J     = (float*)alloc((size_t)NN * LD * 4);

    float* sum0   = stats;        float* sq0    = stats + 128;
    float* sum1   = stats + 256;  float* sq1    = stats + 512;
    float* scale0 = stats + 768;  float* shift0 = stats + 896;
    float* scale1 = stats + 1024; float* shift1 = stats + 1280;

    const int EB = (E1N + E2N + 255) / 256;

    // CSR build
    zero_kernel<<<(NN + 255) / 256, 256, 0, stream>>>(cur1, NN, cur2, NN, stats, 768);
    hist_kernel<<<EB, 256, 0, stream>>>(e1_row, e2_row, cur1, cur2);
    scan_kernel<<<2, 1024, 0, stream>>>(cur1, rp1, cur2, rp2);
    scatter_kernel<<<EB, 256, 0, stream>>>(e1_row, e1_col, e1_val, e2_row, e2_col, e2_val,
                                           cur1, cs1, vs1, cur2, cs2, vs2);

    // embed -> J[:,0:64)
    embed_kernel<<<RB, 256, 0, stream>>>(x, W_emb, b_emb, J);

    // conv0 -> J[:,64:192), then BN
    spmm_dual_kernel<1><<<2 * RB, 256, 0, stream>>>(rp1, cs1, vs1, rp2, cs2, vs2, J, J, 64);
    bn_stats_kernel<128><<<256, 256, 0, stream>>>(J + 64, sum0, sq0);
    bn_finalize_kernel<<<1, 128, 0, stream>>>(sum0, sq0, bn0_g, bn0_b, scale0, shift0, 128);
    bn_apply_kernel<128><<<(NN * 32 + 255) / 256, 256, 0, stream>>>(J + 64, scale0, shift0);

    // conv1 -> J[:,192:448), then BN
    spmm_dual_kernel<2><<<2 * RB, 256, 0, stream>>>(rp1, cs1, vs1, rp2, cs2, vs2, J + 64, J, 192);
    bn_stats_kernel<256><<<256, 256, 0, stream>>>(J + 192, sum1, sq1);
    bn_finalize_kernel<<<1, 256, 0, stream>>>(sum1, sq1, bn1_g, bn1_b, scale1, shift1, 256);
    bn_apply_kernel<256><<<(NN * 64 + 255) / 256, 256, 0, stream>>>(J + 192, scale1, shift1);

    // conv2 -> J[:,448:960)
    spmm_dual_kernel<4><<<2 * RB, 256, 0, stream>>>(rp1, cs1, vs1, rp2, cs2, vs2, J + 192, J, 448);

    // head
    head_kernel<<<(NN + 31) / 32, 256, 0, stream>>>(J, W_head, b_head, out);
}

// Round 3
// 1302.835 us; speedup vs baseline: 1.4574x; 1.2130x over previous
//
#include <hip/hip_runtime.h>

// H2GCN forward, bf16 activation storage.
// One fused bf16 buffer Jh[N, 960]: cols [0,64)=h [64,192)=c0 [192,448)=c1 [448,960)=c2.
// SPMM: gather bf16, accumulate fp32, store bf16. BN on bf16 in-place.
// Head: bf16 j (uint4 = 8 vals / load) x fp32 W. CSR rebuilt in-workspace each call.

#define NN  50000
#define E1N 800000
#define E2N 1600000
#define LD  960          // Jh leading dimension (elements)
#define RB  12500        // (NN+3)/4 row-blocks for spmm

__device__ __forceinline__ float bfl(unsigned int w) {            // low bf16 of packed pair
    return __uint_as_float(w << 16);
}
__device__ __forceinline__ float bfh(unsigned int w) {            // high bf16 of packed pair
    return __uint_as_float(w & 0xFFFF0000u);
}
__device__ __forceinline__ float bf2f(unsigned short u) {
    return __uint_as_float(((unsigned int)u) << 16);
}
__device__ __forceinline__ unsigned short f2bf(float f) {         // round-to-nearest-even
    unsigned int u = __float_as_uint(f);
    u += 0x7FFFu + ((u >> 16) & 1u);
    return (unsigned short)(u >> 16);
}
__device__ __forceinline__ unsigned int pack2(float a, float b) {
    return (unsigned int)f2bf(a) | ((unsigned int)f2bf(b) << 16);
}

// ---------------- setup kernels ----------------

__global__ __launch_bounds__(256) void zero_kernel(int* a, int na, int* b, int nb, float* c, int nc) {
    int i = blockIdx.x * 256 + threadIdx.x;
    if (i < na) a[i] = 0;
    if (i < nb) b[i] = 0;
    if (i < nc) c[i] = 0.f;
}

__global__ __launch_bounds__(256) void hist_kernel(const int* __restrict__ r1, const int* __restrict__ r2,
                                                   int* h1, int* h2) {
    int i = blockIdx.x * 256 + threadIdx.x;
    if (i < E1N) atomicAdd(&h1[r1[i]], 1);
    else if (i < E1N + E2N) atomicAdd(&h2[r2[i - E1N]], 1);
}

__global__ __launch_bounds__(1024) void scan_kernel(int* hist1, int* rp1, int* hist2, int* rp2) {
    int* hist = blockIdx.x ? hist2 : hist1;
    int* rp   = blockIdx.x ? rp2   : rp1;
    const int t = threadIdx.x;
    const int CH = 49;                       // 1024*49 >= 50000
    int base = t * CH;
    int lim = NN - base; if (lim > CH) lim = CH; if (lim < 0) lim = 0;
    int lsum = 0;
    for (int j = 0; j < lim; j++) lsum += hist[base + j];
    __shared__ int s[1024];
    s[t] = lsum;
    __syncthreads();
    for (int off = 1; off < 1024; off <<= 1) {
        int v = (t >= off) ? s[t - off] : 0;
        __syncthreads();
        s[t] += v;
        __syncthreads();
    }
    int run = s[t] - lsum;                   // exclusive prefix
    for (int j = 0; j < lim; j++) {
        int hv = hist[base + j];             // read before overwrite (alias: cursor)
        rp[base + j]   = run;
        hist[base + j] = run;                // cursor init
        run += hv;
    }
    if (t == 0) rp[NN] = s[1023];
}

__global__ __launch_bounds__(256) void scatter_kernel(
        const int* __restrict__ r1, const int* __restrict__ c1, const float* __restrict__ v1,
        const int* __restrict__ r2, const int* __restrict__ c2, const float* __restrict__ v2,
        int* cur1, int* cs1, float* vs1, int* cur2, int* cs2, float* vs2) {
    int i = blockIdx.x * 256 + threadIdx.x;
    if (i < E1N) {
        int r = r1[i];
        int idx = atomicAdd(&cur1[r], 1);
        cs1[idx] = c1[i]; vs1[idx] = v1[i];
    } else if (i < E1N + E2N) {
        int k = i - E1N;
        int r = r2[k];
        int idx = atomicAdd(&cur2[r], 1);
        cs2[idx] = c2[k]; vs2[idx] = v2[k];
    }
}

// ---------------- dense embed: Jh[:,0:64] = relu(x @ W_embed + b), bf16 ----------------
__global__ __launch_bounds__(256) void embed_kernel(const float* __restrict__ x, const float* __restrict__ W,
                                                    const float* __restrict__ b, unsigned short* __restrict__ Jh) {
    int col  = threadIdx.x & 63;
    int node = blockIdx.x * 4 + (threadIdx.x >> 6);
    if (node >= NN) return;
    const float* xr = x + (size_t)node * 256;
    float acc = 0.f;
    #pragma unroll 4
    for (int k = 0; k < 256; k += 4) {
        float4 xv = *(const float4*)(xr + k);
        acc = fmaf(xv.x, W[(k + 0) * 64 + col], acc);
        acc = fmaf(xv.y, W[(k + 1) * 64 + col], acc);
        acc = fmaf(xv.z, W[(k + 2) * 64 + col], acc);
        acc = fmaf(xv.w, W[(k + 3) * 64 + col], acc);
    }
    acc += b[col];
    Jh[(size_t)node * LD + col] = f2bf(fmaxf(acc, 0.f));
}

// ---------------- pull SPMM, both graphs in one launch, bf16 gather ----------------
// wave-per-row; lane owns VEC consecutive features of a 64*VEC-wide src slice.
// blockIdx.x < RB -> graph1 (dst slice), else graph2 (dst slice + 64*VEC cols).
template <int VEC>
__global__ __launch_bounds__(256) void spmm_dual_kernel(
        const int* __restrict__ rp1, const int* __restrict__ cs1, const float* __restrict__ vs1,
        const int* __restrict__ rp2, const int* __restrict__ cs2, const float* __restrict__ vs2,
        const unsigned short* __restrict__ src,   // Jh + src col offset
        unsigned short* __restrict__ dst) {       // Jh + dst col offset (graph1 base)
    int g    = (blockIdx.x >= RB) ? 1 : 0;
    int bx   = blockIdx.x - g * RB;
    int lane = threadIdx.x & 63;
    int row  = bx * 4 + (threadIdx.x >> 6);
    if (row >= NN) return;
    const int*   rp = g ? rp2 : rp1;
    const int*   cs = g ? cs2 : cs1;
    const float* vs = g ? vs2 : vs1;
    int beg = rp[row], end = rp[row + 1];

    float acc[VEC];
    #pragma unroll
    for (int u = 0; u < VEC; u++) acc[u] = 0.f;
    const unsigned short* sbase = src + lane * VEC;

    int j = beg;
    for (; j + 4 <= end; j += 4) {
        int   cA = cs[j+0], cB = cs[j+1], cC = cs[j+2], cD = cs[j+3];
        float vA = vs[j+0], vB = vs[j+1], vC = vs[j+2], vD = vs[j+3];
        const unsigned short* pA = sbase + (size_t)cA * LD;
        const unsigned short* pB = sbase + (size_t)cB * LD;
        const unsigned short* pC = sbase + (size_t)cC * LD;
        const unsigned short* pD = sbase + (size_t)cD * LD;
        if constexpr (VEC == 4) {
            uint2 a = *(const uint2*)pA; uint2 b = *(const uint2*)pB;
            uint2 c = *(const uint2*)pC; uint2 d = *(const uint2*)pD;
            acc[0]=fmaf(vA,bfl(a.x),acc[0]); acc[1]=fmaf(vA,bfh(a.x),acc[1]);
            acc[2]=fmaf(vA,bfl(a.y),acc[2]); acc[3]=fmaf(vA,bfh(a.y),acc[3]);
            acc[0]=fmaf(vB,bfl(b.x),acc[0]); acc[1]=fmaf(vB,bfh(b.x),acc[1]);
            acc[2]=fmaf(vB,bfl(b.y),acc[2]); acc[3]=fmaf(vB,bfh(b.y),acc[3]);
            acc[0]=fmaf(vC,bfl(c.x),acc[0]); acc[1]=fmaf(vC,bfh(c.x),acc[1]);
            acc[2]=fmaf(vC,bfl(c.y),acc[2]); acc[3]=fmaf(vC,bfh(c.y),acc[3]);
            acc[0]=fmaf(vD,bfl(d.x),acc[0]); acc[1]=fmaf(vD,bfh(d.x),acc[1]);
            acc[2]=fmaf(vD,bfl(d.y),acc[2]); acc[3]=fmaf(vD,bfh(d.y),acc[3]);
        } else if constexpr (VEC == 2) {
            unsigned int a = *(const unsigned int*)pA; unsigned int b = *(const unsigned int*)pB;
            unsigned int c = *(const unsigned int*)pC; unsigned int d = *(const unsigned int*)pD;
            acc[0]=fmaf(vA,bfl(a),acc[0]); acc[1]=fmaf(vA,bfh(a),acc[1]);
            acc[0]=fmaf(vB,bfl(b),acc[0]); acc[1]=fmaf(vB,bfh(b),acc[1]);
            acc[0]=fmaf(vC,bfl(c),acc[0]); acc[1]=fmaf(vC,bfh(c),acc[1]);
            acc[0]=fmaf(vD,bfl(d),acc[0]); acc[1]=fmaf(vD,bfh(d),acc[1]);
        } else {
            float sA = bf2f(*pA), sB = bf2f(*pB), sC = bf2f(*pC), sD = bf2f(*pD);
            acc[0]=fmaf(vA,sA,acc[0]); acc[0]=fmaf(vB,sB,acc[0]);
            acc[0]=fmaf(vC,sC,acc[0]); acc[0]=fmaf(vD,sD,acc[0]);
        }
    }
    for (; j < end; j++) {
        int c = cs[j]; float v = vs[j];
        const unsigned short* p = sbase + (size_t)c * LD;
        if constexpr (VEC == 4) {
            uint2 s = *(const uint2*)p;
            acc[0]=fmaf(v,bfl(s.x),acc[0]); acc[1]=fmaf(v,bfh(s.x),acc[1]);
            acc[2]=fmaf(v,bfl(s.y),acc[2]); acc[3]=fmaf(v,bfh(s.y),acc[3]);
        } else if constexpr (VEC == 2) {
            unsigned int s = *(const unsigned int*)p;
            acc[0]=fmaf(v,bfl(s),acc[0]); acc[1]=fmaf(v,bfh(s),acc[1]);
        } else {
            acc[0] = fmaf(v, bf2f(*p), acc[0]);
        }
    }

    unsigned short* dp = dst + (size_t)row * LD + g * (64 * VEC) + lane * VEC;
    if constexpr (VEC == 4) {
        uint2 o; o.x = pack2(acc[0], acc[1]); o.y = pack2(acc[2], acc[3]);
        *(uint2*)dp = o;
    } else if constexpr (VEC == 2) {
        *(unsigned int*)dp = pack2(acc[0], acc[1]);
    } else {
        dp[0] = f2bf(acc[0]);
    }
}

// ---------------- BN stats / finalize / apply (bf16 slice of Jh) ----------------
template <int F>
__global__ __launch_bounds__(256) void bn_stats_kernel(const unsigned short* __restrict__ c,
                                                       float* sum, float* sumsq) {
    constexpr int SL = 256 / F;              // slices per block
    int f  = threadIdx.x % F;
    int sl = threadIdx.x / F;
    float s = 0.f, ss = 0.f;
    for (int r = blockIdx.x * SL + sl; r < NN; r += gridDim.x * SL) {
        float v = bf2f(c[(size_t)r * LD + f]);
        s += v; ss += v * v;
    }
    __shared__ float ls[256], lss[256];
    ls[threadIdx.x] = s; lss[threadIdx.x] = ss;
    __syncthreads();
    if (sl == 0) {
        #pragma unroll
        for (int u = 1; u < SL; u++) { s += ls[f + u * F]; ss += lss[f + u * F]; }
        atomicAdd(&sum[f], s);
        atomicAdd(&sumsq[f], ss);
    }
}

__global__ void bn_finalize_kernel(const float* sum, const float* sumsq, const float* __restrict__ gamma,
                                   const float* __restrict__ beta, float* scale, float* shift, int F) {
    int f = blockIdx.x * blockDim.x + threadIdx.x;
    if (f >= F) return;
    float m   = sum[f] * (1.0f / NN);
    float var = sumsq[f] * (1.0f / NN) - m * m;
    float sc  = gamma[f] * rsqrtf(var + 1e-5f);
    scale[f] = sc;
    shift[f] = beta[f] - m * sc;
}

template <int F>
__global__ __launch_bounds__(256) void bn_apply_kernel(unsigned short* __restrict__ c,
                                                       const float* __restrict__ scale,
                                                       const float* __restrict__ shift) {
    constexpr int FV = F / 4;                // 4-feature groups per node
    int idx  = blockIdx.x * 256 + threadIdx.x;
    int node = idx / FV;
    int fo   = (idx % FV) * 4;
    if (node >= NN) return;
    unsigned short* p = c + (size_t)node * LD + fo;
    uint2 v = *(uint2*)p;
    float a0 = bfl(v.x), a1 = bfh(v.x), a2 = bfl(v.y), a3 = bfh(v.y);
    float4 sc = *(const float4*)(scale + fo);
    float4 sh = *(const float4*)(shift + fo);
    a0 = fmaf(a0, sc.x, sh.x);
    a1 = fmaf(a1, sc.y, sh.y);
    a2 = fmaf(a2, sc.z, sh.z);
    a3 = fmaf(a3, sc.w, sh.w);
    v.x = pack2(a0, a1); v.y = pack2(a2, a3);
    *(uint2*)p = v;
}

// ---------------- head GEMM: out = Jh @ W_head + b (bf16 j, fp32 W) ----------------
__global__ __launch_bounds__(256) void head_kernel(const unsigned short* __restrict__ Jh,
                                                   const float* __restrict__ W,
                                                   const float* __restrict__ b, float* __restrict__ out) {
    int cg   = (threadIdx.x & 7) * 4;              // col 0,4,...,28
    int node = blockIdx.x * 32 + (threadIdx.x >> 3);
    if (node >= NN) return;
    const unsigned short* v = Jh + (size_t)node * LD;
    float4 acc = make_float4(0.f, 0.f, 0.f, 0.f);
    #pragma unroll 2
    for (int k = 0; k < 960; k += 8) {
        uint4 jv = *(const uint4*)(v + k);         // 8 bf16
        float j0 = bfl(jv.x), j1 = bfh(jv.x), j2 = bfl(jv.y), j3 = bfh(jv.y);
        float j4 = bfl(jv.z), j5 = bfh(jv.z), j6 = bfl(jv.w), j7 = bfh(jv.w);
        float4 w0 = *(const float4*)(W + (k + 0) * 32 + cg);
        float4 w1 = *(const float4*)(W + (k + 1) * 32 + cg);
        float4 w2 = *(const float4*)(W + (k + 2) * 32 + cg);
        float4 w3 = *(const float4*)(W + (k + 3) * 32 + cg);
        float4 w4 = *(const float4*)(W + (k + 4) * 32 + cg);
        float4 w5 = *(const float4*)(W + (k + 5) * 32 + cg);
        float4 w6 = *(const float4*)(W + (k + 6) * 32 + cg);
        float4 w7 = *(const float4*)(W + (k + 7) * 32 + cg);
        acc.x=fmaf(j0,w0.x,acc.x); acc.y=fmaf(j0,w0.y,acc.y); acc.z=fmaf(j0,w0.z,acc.z); acc.w=fmaf(j0,w0.w,acc.w);
        acc.x=fmaf(j1,w1.x,acc.x); acc.y=fmaf(j1,w1.y,acc.y); acc.z=fmaf(j1,w1.z,acc.z); acc.w=fmaf(j1,w1.w,acc.w);
        acc.x=fmaf(j2,w2.x,acc.x); acc.y=fmaf(j2,w2.y,acc.y); acc.z=fmaf(j2,w2.z,acc.z); acc.w=fmaf(j2,w2.w,acc.w);
        acc.x=fmaf(j3,w3.x,acc.x); acc.y=fmaf(j3,w3.y,acc.y); acc.z=fmaf(j3,w3.z,acc.z); acc.w=fmaf(j3,w3.w,acc.w);
        acc.x=fmaf(j4,w4.x,acc.x); acc.y=fmaf(j4,w4.y,acc.y); acc.z=fmaf(j4,w4.z,acc.z); acc.w=fmaf(j4,w4.w,acc.w);
        acc.x=fmaf(j5,w5.x,acc.x); acc.y=fmaf(j5,w5.y,acc.y); acc.z=fmaf(j5,w5.z,acc.z); acc.w=fmaf(j5,w5.w,acc.w);
        acc.x=fmaf(j6,w6.x,acc.x); acc.y=fmaf(j6,w6.y,acc.y); acc.z=fmaf(j6,w6.z,acc.z); acc.w=fmaf(j6,w6.w,acc.w);
        acc.x=fmaf(j7,w7.x,acc.x); acc.y=fmaf(j7,w7.y,acc.y); acc.z=fmaf(j7,w7.z,acc.z); acc.w=fmaf(j7,w7.w,acc.w);
    }
    float4 bb = *(const float4*)(b + cg);
    acc.x += bb.x; acc.y += bb.y; acc.z += bb.z; acc.w += bb.w;
    *(float4*)(out + (size_t)node * 32 + cg) = acc;
}

// ---------------- launch ----------------

extern "C" void kernel_launch(void* const* d_in, const int* in_sizes, int n_in,
                              void* d_out, int out_size, void* d_ws, size_t ws_size,
                              hipStream_t stream) {
    const float* x      = (const float*)d_in[0];
    const int*   e1_row = (const int*)d_in[1];
    const int*   e1_col = (const int*)d_in[2];
    const float* e1_val = (const float*)d_in[3];
    const int*   e2_row = (const int*)d_in[4];
    const int*   e2_col = (const int*)d_in[5];
    const float* e2_val = (const float*)d_in[6];
    const float* W_emb  = (const float*)d_in[7];
    const float* b_emb  = (const float*)d_in[8];
    const float* bn0_g  = (const float*)d_in[9];
    const float* bn0_b  = (const float*)d_in[10];
    const float* bn1_g  = (const float*)d_in[11];
    const float* bn1_b  = (const float*)d_in[12];
    const float* W_head = (const float*)d_in[13];
    const float* b_head = (const float*)d_in[14];
    float* out = (float*)d_out;

    char* ws = (char*)d_ws;
    auto alloc = [&](size_t bytes) -> char* {
        char* p = ws;
        ws += (bytes + 255) & ~(size_t)255;
        return p;
    };
    int*   rp1   = (int*)alloc((NN + 1) * 4);
    int*   cur1  = (int*)alloc(NN * 4);
    int*   rp2   = (int*)alloc((NN + 1) * 4);
    int*   cur2  = (int*)alloc(NN * 4);
    int*   cs1   = (int*)alloc(E1N * 4);
    float* vs1   = (float*)alloc(E1N * 4);
    int*   cs2   = (int*)alloc(E2N * 4);
    float* vs2   = (float*)alloc(E2N * 4);
    float* stats = (float*)alloc(1536 * 4);
    unsigned short* Jh = (unsigned short*)alloc((size_t)NN * LD * 2);

    float* sum0   = stats;        float* sq0    = stats + 128;
    float* sum1   = stats + 256;  float* sq1    = stats + 512;
    float* scale0 = stats + 768;  float* shift0 = stats + 896;
    float* scale1 = stats + 1024; float* shift1 = stats + 1280;

    const int EB = (E1N + E2N + 255) / 256;

    // CSR build
    zero_kernel<<<(NN + 255) / 256, 256, 0, stream>>>(cur1, NN, cur2, NN, stats, 768);
    hist_kernel<<<EB, 256, 0, stream>>>(e1_row, e2_row, cur1, cur2);
    scan_kernel<<<2, 1024, 0, stream>>>(cur1, rp1, cur2, rp2);
    scatter_kernel<<<EB, 256, 0, stream>>>(e1_row, e1_col, e1_val, e2_row, e2_col, e2_val,
                                           cur1, cs1, vs1, cur2, cs2, vs2);

    // embed -> Jh[:,0:64)
    embed_kernel<<<RB, 256, 0, stream>>>(x, W_emb, b_emb, Jh);

    // conv0 -> Jh[:,64:192), then BN
    spmm_dual_kernel<1><<<2 * RB, 256, 0, stream>>>(rp1, cs1, vs1, rp2, cs2, vs2, Jh, Jh + 64);
    bn_stats_kernel<128><<<256, 256, 0, stream>>>(Jh + 64, sum0, sq0);
    bn_finalize_kernel<<<1, 128, 0, stream>>>(sum0, sq0, bn0_g, bn0_b, scale0, shift0, 128);
    bn_apply_kernel<128><<<(NN * 32 + 255) / 256, 256, 0, stream>>>(Jh + 64, scale0, shift0);

    // conv1 -> Jh[:,192:448), then BN
    spmm_dual_kernel<2><<<2 * RB, 256, 0, stream>>>(rp1, cs1, vs1, rp2, cs2, vs2, Jh + 64, Jh + 192);
    bn_stats_kernel<256><<<256, 256, 0, stream>>>(Jh + 192, sum1, sq1);
    bn_finalize_kernel<<<1, 256, 0, stream>>>(sum1, sq1, bn1_g, bn1_b, scale1, shift1, 256);
    bn_apply_kernel<256><<<(NN * 64 + 255) / 256, 256, 0, stream>>>(Jh + 192, scale1, shift1);

    // conv2 -> Jh[:,448:960)
    spmm_dual_kernel<4><<<2 * RB, 256, 0, stream>>>(rp1, cs1, vs1, rp2, cs2, vs2, Jh + 192, Jh + 448);

    // head
    head_kernel<<<(NN + 31) / 32, 256, 0, stream>>>(Jh, W_head, b_head, out);
}

// Round 4
// 1107.351 us; speedup vs baseline: 1.7146x; 1.1765x over previous
//
#include <hip/hip_runtime.h>

// H2GCN forward, bf16 activations in fused Jh[N,960]:
//   cols [0,64)=h [64,192)=c0 [192,448)=c1 [448,960)=c2.
// SPMM: gather bf16 / accumulate fp32 / store bf16, 8-edge unrolled for MLP.
// Head: MFMA 16x16x32 bf16 — W_head pre-packed to B-fragment layout per call.

#define NN  50000
#define E1N 800000
#define E2N 1600000
#define LD  960
#define RB  12500        // (NN+3)/4 row-blocks for spmm

typedef short bf16x8 __attribute__((ext_vector_type(8)));
typedef float f32x4  __attribute__((ext_vector_type(4)));

__device__ __forceinline__ float bfl(unsigned int w) { return __uint_as_float(w << 16); }
__device__ __forceinline__ float bfh(unsigned int w) { return __uint_as_float(w & 0xFFFF0000u); }
__device__ __forceinline__ float bf2f(unsigned short u) { return __uint_as_float(((unsigned int)u) << 16); }
__device__ __forceinline__ unsigned short f2bf(float f) {         // RNE
    unsigned int u = __float_as_uint(f);
    u += 0x7FFFu + ((u >> 16) & 1u);
    return (unsigned short)(u >> 16);
}
__device__ __forceinline__ unsigned int pack2(float a, float b) {
    return (unsigned int)f2bf(a) | ((unsigned int)f2bf(b) << 16);
}

// ---------------- setup kernels ----------------

__global__ __launch_bounds__(256) void zero_kernel(int* a, int na, int* b, int nb, float* c, int nc) {
    int i = blockIdx.x * 256 + threadIdx.x;
    if (i < na) a[i] = 0;
    if (i < nb) b[i] = 0;
    if (i < nc) c[i] = 0.f;
}

__global__ __launch_bounds__(256) void hist_kernel(const int* __restrict__ r1, const int* __restrict__ r2,
                                                   int* h1, int* h2) {
    int i = blockIdx.x * 256 + threadIdx.x;
    if (i < E1N) atomicAdd(&h1[r1[i]], 1);
    else if (i < E1N + E2N) atomicAdd(&h2[r2[i - E1N]], 1);
}

__global__ __launch_bounds__(1024) void scan_kernel(int* hist1, int* rp1, int* hist2, int* rp2) {
    int* hist = blockIdx.x ? hist2 : hist1;
    int* rp   = blockIdx.x ? rp2   : rp1;
    const int t = threadIdx.x;
    const int CH = 49;
    int base = t * CH;
    int lim = NN - base; if (lim > CH) lim = CH; if (lim < 0) lim = 0;
    int lsum = 0;
    for (int j = 0; j < lim; j++) lsum += hist[base + j];
    __shared__ int s[1024];
    s[t] = lsum;
    __syncthreads();
    for (int off = 1; off < 1024; off <<= 1) {
        int v = (t >= off) ? s[t - off] : 0;
        __syncthreads();
        s[t] += v;
        __syncthreads();
    }
    int run = s[t] - lsum;
    for (int j = 0; j < lim; j++) {
        int hv = hist[base + j];
        rp[base + j]   = run;
        hist[base + j] = run;
        run += hv;
    }
    if (t == 0) rp[NN] = s[1023];
}

__global__ __launch_bounds__(256) void scatter_kernel(
        const int* __restrict__ r1, const int* __restrict__ c1, const float* __restrict__ v1,
        const int* __restrict__ r2, const int* __restrict__ c2, const float* __restrict__ v2,
        int* cur1, int* cs1, float* vs1, int* cur2, int* cs2, float* vs2) {
    int i = blockIdx.x * 256 + threadIdx.x;
    if (i < E1N) {
        int r = r1[i];
        int idx = atomicAdd(&cur1[r], 1);
        cs1[idx] = c1[i]; vs1[idx] = v1[i];
    } else if (i < E1N + E2N) {
        int k = i - E1N;
        int r = r2[k];
        int idx = atomicAdd(&cur2[r], 1);
        cs2[idx] = c2[k]; vs2[idx] = v2[k];
    }
}

// ---------------- W_head -> bf16 B-fragment pack ----------------
// Wb[((ctile*30 + kb)*64 + lane)*8 + j] = bf16(W[kb*32 + (lane>>4)*8 + j][ctile*16 + (lane&15)])
__global__ __launch_bounds__(256) void packw_kernel(const float* __restrict__ W, unsigned short* __restrict__ Wb) {
    int i = blockIdx.x * 256 + threadIdx.x;          // (ctile,kb,lane) flat, 2*30*64 = 3840
    if (i >= 3840) return;
    int lane  = i & 63;
    int kb    = (i >> 6) % 30;
    int ctile = i / (30 * 64);
    int n  = ctile * 16 + (lane & 15);
    int k0 = kb * 32 + (lane >> 4) * 8;
    unsigned short v[8];
    #pragma unroll
    for (int j = 0; j < 8; j++) v[j] = f2bf(W[(k0 + j) * 32 + n]);
    *(uint4*)(Wb + (size_t)i * 8) = *(uint4*)v;
}

// ---------------- dense embed: Jh[:,0:64] = relu(x @ W_embed + b), bf16 ----------------
__global__ __launch_bounds__(256) void embed_kernel(const float* __restrict__ x, const float* __restrict__ W,
                                                    const float* __restrict__ b, unsigned short* __restrict__ Jh) {
    int col  = threadIdx.x & 63;
    int node = blockIdx.x * 4 + (threadIdx.x >> 6);
    if (node >= NN) return;
    const float* xr = x + (size_t)node * 256;
    float acc = 0.f;
    #pragma unroll 4
    for (int k = 0; k < 256; k += 4) {
        float4 xv = *(const float4*)(xr + k);
        acc = fmaf(xv.x, W[(k + 0) * 64 + col], acc);
        acc = fmaf(xv.y, W[(k + 1) * 64 + col], acc);
        acc = fmaf(xv.z, W[(k + 2) * 64 + col], acc);
        acc = fmaf(xv.w, W[(k + 3) * 64 + col], acc);
    }
    acc += b[col];
    Jh[(size_t)node * LD + col] = f2bf(fmaxf(acc, 0.f));
}

// ---------------- pull SPMM, both graphs in one launch, bf16 gather ----------------
template <int VEC>
__global__ __launch_bounds__(256) void spmm_dual_kernel(
        const int* __restrict__ rp1, const int* __restrict__ cs1, const float* __restrict__ vs1,
        const int* __restrict__ rp2, const int* __restrict__ cs2, const float* __restrict__ vs2,
        const unsigned short* __restrict__ src,   // Jh + src col offset
        unsigned short* __restrict__ dst) {       // Jh + dst col offset (graph1 base)
    int g    = (blockIdx.x >= RB) ? 1 : 0;
    int bx   = blockIdx.x - g * RB;
    int lane = threadIdx.x & 63;
    int row  = bx * 4 + (threadIdx.x >> 6);
    if (row >= NN) return;
    const int*   rp = g ? rp2 : rp1;
    const int*   cs = g ? cs2 : cs1;
    const float* vs = g ? vs2 : vs1;
    int beg = rp[row], end = rp[row + 1];

    float acc[VEC];
    #pragma unroll
    for (int u = 0; u < VEC; u++) acc[u] = 0.f;
    const unsigned short* sbase = src + lane * VEC;

    int j = beg;
    // 8-edge unrolled main loop: 8 outstanding gathers per wave
    for (; j + 8 <= end; j += 8) {
        int   c[8]; float v[8];
        #pragma unroll
        for (int u = 0; u < 8; u++) { c[u] = cs[j + u]; v[u] = vs[j + u]; }
        if constexpr (VEC == 4) {
            uint2 s[8];
            #pragma unroll
            for (int u = 0; u < 8; u++) s[u] = *(const uint2*)(sbase + (size_t)c[u] * LD);
            #pragma unroll
            for (int u = 0; u < 8; u++) {
                acc[0]=fmaf(v[u],bfl(s[u].x),acc[0]); acc[1]=fmaf(v[u],bfh(s[u].x),acc[1]);
                acc[2]=fmaf(v[u],bfl(s[u].y),acc[2]); acc[3]=fmaf(v[u],bfh(s[u].y),acc[3]);
            }
        } else if constexpr (VEC == 2) {
            unsigned int s[8];
            #pragma unroll
            for (int u = 0; u < 8; u++) s[u] = *(const unsigned int*)(sbase + (size_t)c[u] * LD);
            #pragma unroll
            for (int u = 0; u < 8; u++) {
                acc[0]=fmaf(v[u],bfl(s[u]),acc[0]); acc[1]=fmaf(v[u],bfh(s[u]),acc[1]);
            }
        } else {
            unsigned short s[8];
            #pragma unroll
            for (int u = 0; u < 8; u++) s[u] = sbase[(size_t)c[u] * LD];
            #pragma unroll
            for (int u = 0; u < 8; u++) acc[0] = fmaf(v[u], bf2f(s[u]), acc[0]);
        }
    }
    for (; j < end; j++) {
        int cc = cs[j]; float v = vs[j];
        const unsigned short* p = sbase + (size_t)cc * LD;
        if constexpr (VEC == 4) {
            uint2 s = *(const uint2*)p;
            acc[0]=fmaf(v,bfl(s.x),acc[0]); acc[1]=fmaf(v,bfh(s.x),acc[1]);
            acc[2]=fmaf(v,bfl(s.y),acc[2]); acc[3]=fmaf(v,bfh(s.y),acc[3]);
        } else if constexpr (VEC == 2) {
            unsigned int s = *(const unsigned int*)p;
            acc[0]=fmaf(v,bfl(s),acc[0]); acc[1]=fmaf(v,bfh(s),acc[1]);
        } else {
            acc[0] = fmaf(v, bf2f(*p), acc[0]);
        }
    }

    unsigned short* dp = dst + (size_t)row * LD + g * (64 * VEC) + lane * VEC;
    if constexpr (VEC == 4) {
        uint2 o; o.x = pack2(acc[0], acc[1]); o.y = pack2(acc[2], acc[3]);
        *(uint2*)dp = o;
    } else if constexpr (VEC == 2) {
        *(unsigned int*)dp = pack2(acc[0], acc[1]);
    } else {
        dp[0] = f2bf(acc[0]);
    }
}

// ---------------- BN stats / finalize / apply (bf16 slice of Jh) ----------------
template <int F>
__global__ __launch_bounds__(256) void bn_stats_kernel(const unsigned short* __restrict__ c,
                                                       float* sum, float* sumsq) {
    constexpr int SL = 256 / F;
    int f  = threadIdx.x % F;
    int sl = threadIdx.x / F;
    float s = 0.f, ss = 0.f;
    for (int r = blockIdx.x * SL + sl; r < NN; r += gridDim.x * SL) {
        float v = bf2f(c[(size_t)r * LD + f]);
        s += v; ss += v * v;
    }
    __shared__ float ls[256], lss[256];
    ls[threadIdx.x] = s; lss[threadIdx.x] = ss;
    __syncthreads();
    if (sl == 0) {
        #pragma unroll
        for (int u = 1; u < SL; u++) { s += ls[f + u * F]; ss += lss[f + u * F]; }
        atomicAdd(&sum[f], s);
        atomicAdd(&sumsq[f], ss);
    }
}

__global__ void bn_finalize_kernel(const float* sum, const float* sumsq, const float* __restrict__ gamma,
                                   const float* __restrict__ beta, float* scale, float* shift, int F) {
    int f = blockIdx.x * blockDim.x + threadIdx.x;
    if (f >= F) return;
    float m   = sum[f] * (1.0f / NN);
    float var = sumsq[f] * (1.0f / NN) - m * m;
    float sc  = gamma[f] * rsqrtf(var + 1e-5f);
    scale[f] = sc;
    shift[f] = beta[f] - m * sc;
}

template <int F>
__global__ __launch_bounds__(256) void bn_apply_kernel(unsigned short* __restrict__ c,
                                                       const float* __restrict__ scale,
                                                       const float* __restrict__ shift) {
    constexpr int FV = F / 4;
    int idx  = blockIdx.x * 256 + threadIdx.x;
    int node = idx / FV;
    int fo   = (idx % FV) * 4;
    if (node >= NN) return;
    unsigned short* p = c + (size_t)node * LD + fo;
    uint2 v = *(uint2*)p;
    float a0 = bfl(v.x), a1 = bfh(v.x), a2 = bfl(v.y), a3 = bfh(v.y);
    float4 sc = *(const float4*)(scale + fo);
    float4 sh = *(const float4*)(shift + fo);
    a0 = fmaf(a0, sc.x, sh.x);
    a1 = fmaf(a1, sc.y, sh.y);
    a2 = fmaf(a2, sc.z, sh.z);
    a3 = fmaf(a3, sc.w, sh.w);
    v.x = pack2(a0, a1); v.y = pack2(a2, a3);
    *(uint2*)p = v;
}

// ---------------- head GEMM via MFMA: out = Jh @ W_head + b ----------------
// wave = one 16-node tile, both 16-col tiles. K=960 -> 30 steps of 16x16x32.
// A-frag: lane holds Jh[tile*16 + (lane&15)][k0 + (lane>>4)*8 + j], j=0..7 (uint4).
// B-frag: pre-packed Wb, fully coalesced. C/D: col=lane&15, row=(lane>>4)*4+reg.
__global__ __launch_bounds__(256) void head_mfma_kernel(const unsigned short* __restrict__ Jh,
                                                        const unsigned short* __restrict__ Wb,
                                                        const float* __restrict__ b,
                                                        float* __restrict__ out) {
    int wave = threadIdx.x >> 6;
    int lane = threadIdx.x & 63;
    int tile = blockIdx.x * 4 + wave;                 // 3125 node tiles (50000 = 16*3125)
    if (tile >= 3125) return;
    int m = lane & 15;
    int q = lane >> 4;
    const unsigned short* arow  = Jh + (size_t)(tile * 16 + m) * LD + q * 8;
    const unsigned short* bbase = Wb + (size_t)lane * 8;
    f32x4 acc0 = {0.f, 0.f, 0.f, 0.f};
    f32x4 acc1 = {0.f, 0.f, 0.f, 0.f};
    #pragma unroll 5
    for (int kb = 0; kb < 30; kb++) {
        bf16x8 a  = *(const bf16x8*)(arow + kb * 32);
        bf16x8 b0 = *(const bf16x8*)(bbase + (size_t)kb * 512);
        bf16x8 b1 = *(const bf16x8*)(bbase + (size_t)(30 + kb) * 512);
        acc0 = __builtin_amdgcn_mfma_f32_16x16x32_bf16(a, b0, acc0, 0, 0, 0);
        acc1 = __builtin_amdgcn_mfma_f32_16x16x32_bf16(a, b1, acc1, 0, 0, 0);
    }
    int col = m;
    float b0 = b[col], b1 = b[16 + col];
    #pragma unroll
    for (int r = 0; r < 4; r++) {
        float* op = out + (size_t)(tile * 16 + q * 4 + r) * 32 + col;
        op[0]  = acc0[r] + b0;
        op[16] = acc1[r] + b1;
    }
}

// ---------------- launch ----------------

extern "C" void kernel_launch(void* const* d_in, const int* in_sizes, int n_in,
                              void* d_out, int out_size, void* d_ws, size_t ws_size,
                              hipStream_t stream) {
    const float* x      = (const float*)d_in[0];
    const int*   e1_row = (const int*)d_in[1];
    const int*   e1_col = (const int*)d_in[2];
    const float* e1_val = (const float*)d_in[3];
    const int*   e2_row = (const int*)d_in[4];
    const int*   e2_col = (const int*)d_in[5];
    const float* e2_val = (const float*)d_in[6];
    const float* W_emb  = (const float*)d_in[7];
    const float* b_emb  = (const float*)d_in[8];
    const float* bn0_g  = (const float*)d_in[9];
    const float* bn0_b  = (const float*)d_in[10];
    const float* bn1_g  = (const float*)d_in[11];
    const float* bn1_b  = (const float*)d_in[12];
    const float* W_head = (const float*)d_in[13];
    const float* b_head = (const float*)d_in[14];
    float* out = (float*)d_out;

    char* ws = (char*)d_ws;
    auto alloc = [&](size_t bytes) -> char* {
        char* p = ws;
        ws += (bytes + 255) & ~(size_t)255;
        return p;
    };
    int*   rp1   = (int*)alloc((NN + 1) * 4);
    int*   cur1  = (int*)alloc(NN * 4);
    int*   rp2   = (int*)alloc((NN + 1) * 4);
    int*   cur2  = (int*)alloc(NN * 4);
    int*   cs1   = (int*)alloc(E1N * 4);
    float* vs1   = (float*)alloc(E1N * 4);
    int*   cs2   = (int*)alloc(E2N * 4);
    float* vs2   = (float*)alloc(E2N * 4);
    float* stats = (float*)alloc(1536 * 4);
    unsigned short* Wb = (unsigned short*)alloc(3840 * 8 * 2);
    unsigned short* Jh = (unsigned short*)alloc((size_t)NN * LD * 2);

    float* sum0   = stats;        float* sq0    = stats + 128;
    float* sum1   = stats + 256;  float* sq1    = stats + 512;
    float* scale0 = stats + 768;  float* shift0 = stats + 896;
    float* scale1 = stats + 1024; float* shift1 = stats + 1280;

    const int EB = (E1N + E2N + 255) / 256;

    // CSR build + W pack
    zero_kernel<<<(NN + 255) / 256, 256, 0, stream>>>(cur1, NN, cur2, NN, stats, 768);
    hist_kernel<<<EB, 256, 0, stream>>>(e1_row, e2_row, cur1, cur2);
    scan_kernel<<<2, 1024, 0, stream>>>(cur1, rp1, cur2, rp2);
    scatter_kernel<<<EB, 256, 0, stream>>>(e1_row, e1_col, e1_val, e2_row, e2_col, e2_val,
                                           cur1, cs1, vs1, cur2, cs2, vs2);
    packw_kernel<<<15, 256, 0, stream>>>(W_head, Wb);

    // embed -> Jh[:,0:64)
    embed_kernel<<<RB, 256, 0, stream>>>(x, W_emb, b_emb, Jh);

    // conv0 -> Jh[:,64:192), then BN
    spmm_dual_kernel<1><<<2 * RB, 256, 0, stream>>>(rp1, cs1, vs1, rp2, cs2, vs2, Jh, Jh + 64);
    bn_stats_kernel<128><<<512, 256, 0, stream>>>(Jh + 64, sum0, sq0);
    bn_finalize_kernel<<<1, 128, 0, stream>>>(sum0, sq0, bn0_g, bn0_b, scale0, shift0, 128);
    bn_apply_kernel<128><<<(NN * 32 + 255) / 256, 256, 0, stream>>>(Jh + 64, scale0, shift0);

    // conv1 -> Jh[:,192:448), then BN
    spmm_dual_kernel<2><<<2 * RB, 256, 0, stream>>>(rp1, cs1, vs1, rp2, cs2, vs2, Jh + 64, Jh + 192);
    bn_stats_kernel<256><<<512, 256, 0, stream>>>(Jh + 192, sum1, sq1);
    bn_finalize_kernel<<<1, 256, 0, stream>>>(sum1, sq1, bn1_g, bn1_b, scale1, shift1, 256);
    bn_apply_kernel<256><<<(NN * 64 + 255) / 256, 256, 0, stream>>>(Jh + 192, scale1, shift1);

    // conv2 -> Jh[:,448:960)
    spmm_dual_kernel<4><<<2 * RB, 256, 0, stream>>>(rp1, cs1, vs1, rp2, cs2, vs2, Jh + 192, Jh + 448);

    // head (MFMA)
    head_mfma_kernel<<<(3125 + 3) / 4, 256, 0, stream>>>(Jh, Wb, b_head, out);
}

// Round 5
// 924.971 us; speedup vs baseline: 2.0527x; 1.1972x over previous
//
#include <hip/hip_runtime.h>

// H2GCN forward, bf16 activations in fused Jh[N,960]:
//   cols [0,64)=h [64,192)=c0 [192,448)=c1 [448,960)=c2.
// SPMM: gather bf16 / accumulate fp32 / store bf16, 8-edge unrolled for MLP.
// Embed + Head: MFMA 16x16x32 bf16, weights pre-packed to B-fragment layout per call.

#define NN  50000
#define E1N 800000
#define E2N 1600000
#define LD  960
#define RB  12500        // (NN+3)/4 row-blocks for spmm
#define NT  3125         // 16-node tiles

typedef short bf16x8 __attribute__((ext_vector_type(8)));
typedef float f32x4  __attribute__((ext_vector_type(4)));

__device__ __forceinline__ float bfl(unsigned int w) { return __uint_as_float(w << 16); }
__device__ __forceinline__ float bfh(unsigned int w) { return __uint_as_float(w & 0xFFFF0000u); }
__device__ __forceinline__ float bf2f(unsigned short u) { return __uint_as_float(((unsigned int)u) << 16); }
__device__ __forceinline__ unsigned short f2bf(float f) {         // RNE
    unsigned int u = __float_as_uint(f);
    u += 0x7FFFu + ((u >> 16) & 1u);
    return (unsigned short)(u >> 16);
}
__device__ __forceinline__ unsigned int pack2(float a, float b) {
    return (unsigned int)f2bf(a) | ((unsigned int)f2bf(b) << 16);
}

// ---------------- setup kernels ----------------

__global__ __launch_bounds__(256) void zero_kernel(int* a, int na, int* b, int nb, float* c, int nc) {
    int i = blockIdx.x * 256 + threadIdx.x;
    if (i < na) a[i] = 0;
    if (i < nb) b[i] = 0;
    if (i < nc) c[i] = 0.f;
}

__global__ __launch_bounds__(256) void hist_kernel(const int* __restrict__ r1, const int* __restrict__ r2,
                                                   int* h1, int* h2) {
    int i = blockIdx.x * 256 + threadIdx.x;
    if (i < E1N) atomicAdd(&h1[r1[i]], 1);
    else if (i < E1N + E2N) atomicAdd(&h2[r2[i - E1N]], 1);
}

__global__ __launch_bounds__(1024) void scan_kernel(int* hist1, int* rp1, int* hist2, int* rp2) {
    int* hist = blockIdx.x ? hist2 : hist1;
    int* rp   = blockIdx.x ? rp2   : rp1;
    const int t = threadIdx.x;
    const int CH = 49;
    int base = t * CH;
    int lim = NN - base; if (lim > CH) lim = CH; if (lim < 0) lim = 0;
    int lsum = 0;
    for (int j = 0; j < lim; j++) lsum += hist[base + j];
    __shared__ int s[1024];
    s[t] = lsum;
    __syncthreads();
    for (int off = 1; off < 1024; off <<= 1) {
        int v = (t >= off) ? s[t - off] : 0;
        __syncthreads();
        s[t] += v;
        __syncthreads();
    }
    int run = s[t] - lsum;
    for (int j = 0; j < lim; j++) {
        int hv = hist[base + j];
        rp[base + j]   = run;
        hist[base + j] = run;
        run += hv;
    }
    if (t == 0) rp[NN] = s[1023];
}

__global__ __launch_bounds__(256) void scatter_kernel(
        const int* __restrict__ r1, const int* __restrict__ c1, const float* __restrict__ v1,
        const int* __restrict__ r2, const int* __restrict__ c2, const float* __restrict__ v2,
        int* cur1, int* cs1, float* vs1, int* cur2, int* cs2, float* vs2) {
    int i = blockIdx.x * 256 + threadIdx.x;
    if (i < E1N) {
        int r = r1[i];
        int idx = atomicAdd(&cur1[r], 1);
        cs1[idx] = c1[i]; vs1[idx] = v1[i];
    } else if (i < E1N + E2N) {
        int k = i - E1N;
        int r = r2[k];
        int idx = atomicAdd(&cur2[r], 1);
        cs2[idx] = c2[k]; vs2[idx] = v2[k];
    }
}

// ---------------- weight -> bf16 B-fragment pack ----------------
// Generic: W is [K, NC] row-major fp32; ctiles = NC/16, kbs = K/32.
// Wb[((ctile*kbs + kb)*64 + lane)*8 + j] = bf16(W[kb*32 + (lane>>4)*8 + j][ctile*16 + (lane&15)])
__global__ __launch_bounds__(256) void packw_kernel(const float* __restrict__ W, unsigned short* __restrict__ Wb,
                                                    int NC, int kbs, int total) {
    int i = blockIdx.x * 256 + threadIdx.x;          // (ctile,kb,lane) flat
    if (i >= total) return;
    int lane  = i & 63;
    int kb    = (i >> 6) % kbs;
    int ctile = i / (kbs * 64);
    int n  = ctile * 16 + (lane & 15);
    int k0 = kb * 32 + (lane >> 4) * 8;
    unsigned short v[8];
    #pragma unroll
    for (int j = 0; j < 8; j++) v[j] = f2bf(W[(k0 + j) * NC + n]);
    *(uint4*)(Wb + (size_t)i * 8) = *(uint4*)v;
}

// ---------------- embed via MFMA: Jh[:,0:64] = relu(x @ W_embed + b) ----------------
// wave = 16-node tile x all 64 cols (4 ctiles). K=256 -> 8 steps of 16x16x32.
// A-frag built in-reg from fp32 x (2x float4 per step, converted to bf16).
__global__ __launch_bounds__(256) void embed_mfma_kernel(const float* __restrict__ x,
                                                         const unsigned short* __restrict__ Wb,
                                                         const float* __restrict__ bias,
                                                         unsigned short* __restrict__ Jh) {
    int wave = threadIdx.x >> 6;
    int lane = threadIdx.x & 63;
    int tile = blockIdx.x * 4 + wave;
    if (tile >= NT) return;
    int m = lane & 15;
    int q = lane >> 4;
    const float* xr = x + (size_t)(tile * 16 + m) * 256 + q * 8;
    const unsigned short* bbase = Wb + (size_t)lane * 8;
    f32x4 acc[4];
    #pragma unroll
    for (int ct = 0; ct < 4; ct++) acc[ct] = (f32x4){0.f, 0.f, 0.f, 0.f};
    #pragma unroll
    for (int kb = 0; kb < 8; kb++) {
        float4 xa = *(const float4*)(xr + kb * 32);
        float4 xb = *(const float4*)(xr + kb * 32 + 4);
        unsigned short av[8];
        av[0] = f2bf(xa.x); av[1] = f2bf(xa.y); av[2] = f2bf(xa.z); av[3] = f2bf(xa.w);
        av[4] = f2bf(xb.x); av[5] = f2bf(xb.y); av[6] = f2bf(xb.z); av[7] = f2bf(xb.w);
        bf16x8 a = *(bf16x8*)av;
        #pragma unroll
        for (int ct = 0; ct < 4; ct++) {
            bf16x8 bfr = *(const bf16x8*)(bbase + (size_t)(ct * 8 + kb) * 512);
            acc[ct] = __builtin_amdgcn_mfma_f32_16x16x32_bf16(a, bfr, acc[ct], 0, 0, 0);
        }
    }
    // C/D: col=lane&15 (within ctile), row=q*4+r
    #pragma unroll
    for (int ct = 0; ct < 4; ct++) {
        int col = ct * 16 + m;
        float bb = bias[col];
        #pragma unroll
        for (int r = 0; r < 4; r++) {
            float v = fmaxf(acc[ct][r] + bb, 0.f);
            Jh[(size_t)(tile * 16 + q * 4 + r) * LD + col] = f2bf(v);
        }
    }
}

// ---------------- pull SPMM, both graphs in one launch, bf16 gather ----------------
template <int VEC>
__global__ __launch_bounds__(256) void spmm_dual_kernel(
        const int* __restrict__ rp1, const int* __restrict__ cs1, const float* __restrict__ vs1,
        const int* __restrict__ rp2, const int* __restrict__ cs2, const float* __restrict__ vs2,
        const unsigned short* __restrict__ src,   // Jh + src col offset
        unsigned short* __restrict__ dst) {       // Jh + dst col offset (graph1 base)
    int g    = (blockIdx.x >= RB) ? 1 : 0;
    int bx   = blockIdx.x - g * RB;
    int lane = threadIdx.x & 63;
    int row  = bx * 4 + (threadIdx.x >> 6);
    if (row >= NN) return;
    const int*   rp = g ? rp2 : rp1;
    const int*   cs = g ? cs2 : cs1;
    const float* vs = g ? vs2 : vs1;
    int beg = rp[row], end = rp[row + 1];

    float acc[VEC];
    #pragma unroll
    for (int u = 0; u < VEC; u++) acc[u] = 0.f;
    const unsigned short* sbase = src + lane * VEC;

    int j = beg;
    for (; j + 8 <= end; j += 8) {
        int   c[8]; float v[8];
        #pragma unroll
        for (int u = 0; u < 8; u++) { c[u] = cs[j + u]; v[u] = vs[j + u]; }
        if constexpr (VEC == 4) {
            uint2 s[8];
            #pragma unroll
            for (int u = 0; u < 8; u++) s[u] = *(const uint2*)(sbase + (size_t)c[u] * LD);
            #pragma unroll
            for (int u = 0; u < 8; u++) {
                acc[0]=fmaf(v[u],bfl(s[u].x),acc[0]); acc[1]=fmaf(v[u],bfh(s[u].x),acc[1]);
                acc[2]=fmaf(v[u],bfl(s[u].y),acc[2]); acc[3]=fmaf(v[u],bfh(s[u].y),acc[3]);
            }
        } else if constexpr (VEC == 2) {
            unsigned int s[8];
            #pragma unroll
            for (int u = 0; u < 8; u++) s[u] = *(const unsigned int*)(sbase + (size_t)c[u] * LD);
            #pragma unroll
            for (int u = 0; u < 8; u++) {
                acc[0]=fmaf(v[u],bfl(s[u]),acc[0]); acc[1]=fmaf(v[u],bfh(s[u]),acc[1]);
            }
        } else {
            unsigned short s[8];
            #pragma unroll
            for (int u = 0; u < 8; u++) s[u] = sbase[(size_t)c[u] * LD];
            #pragma unroll
            for (int u = 0; u < 8; u++) acc[0] = fmaf(v[u], bf2f(s[u]), acc[0]);
        }
    }
    for (; j < end; j++) {
        int cc = cs[j]; float v = vs[j];
        const unsigned short* p = sbase + (size_t)cc * LD;
        if constexpr (VEC == 4) {
            uint2 s = *(const uint2*)p;
            acc[0]=fmaf(v,bfl(s.x),acc[0]); acc[1]=fmaf(v,bfh(s.x),acc[1]);
            acc[2]=fmaf(v,bfl(s.y),acc[2]); acc[3]=fmaf(v,bfh(s.y),acc[3]);
        } else if constexpr (VEC == 2) {
            unsigned int s = *(const unsigned int*)p;
            acc[0]=fmaf(v,bfl(s),acc[0]); acc[1]=fmaf(v,bfh(s),acc[1]);
        } else {
            acc[0] = fmaf(v, bf2f(*p), acc[0]);
        }
    }

    unsigned short* dp = dst + (size_t)row * LD + g * (64 * VEC) + lane * VEC;
    if constexpr (VEC == 4) {
        uint2 o; o.x = pack2(acc[0], acc[1]); o.y = pack2(acc[2], acc[3]);
        *(uint2*)dp = o;
    } else if constexpr (VEC == 2) {
        *(unsigned int*)dp = pack2(acc[0], acc[1]);
    } else {
        dp[0] = f2bf(acc[0]);
    }
}

// ---------------- BN stats / finalize / apply (bf16 slice of Jh) ----------------
template <int F>
__global__ __launch_bounds__(256) void bn_stats_kernel(const unsigned short* __restrict__ c,
                                                       float* sum, float* sumsq) {
    constexpr int SL = 256 / F;
    int f  = threadIdx.x % F;
    int sl = threadIdx.x / F;
    float s = 0.f, ss = 0.f;
    for (int r = blockIdx.x * SL + sl; r < NN; r += gridDim.x * SL) {
        float v = bf2f(c[(size_t)r * LD + f]);
        s += v; ss += v * v;
    }
    __shared__ float ls[256], lss[256];
    ls[threadIdx.x] = s; lss[threadIdx.x] = ss;
    __syncthreads();
    if (sl == 0) {
        #pragma unroll
        for (int u = 1; u < SL; u++) { s += ls[f + u * F]; ss += lss[f + u * F]; }
        atomicAdd(&sum[f], s);
        atomicAdd(&sumsq[f], ss);
    }
}

__global__ void bn_finalize_kernel(const float* sum, const float* sumsq, const float* __restrict__ gamma,
                                   const float* __restrict__ beta, float* scale, float* shift, int F) {
    int f = blockIdx.x * blockDim.x + threadIdx.x;
    if (f >= F) return;
    float m   = sum[f] * (1.0f / NN);
    float var = sumsq[f] * (1.0f / NN) - m * m;
    float sc  = gamma[f] * rsqrtf(var + 1e-5f);
    scale[f] = sc;
    shift[f] = beta[f] - m * sc;
}

template <int F>
__global__ __launch_bounds__(256) void bn_apply_kernel(unsigned short* __restrict__ c,
                                                       const float* __restrict__ scale,
                                                       const float* __restrict__ shift) {
    constexpr int FV = F / 4;
    int idx  = blockIdx.x * 256 + threadIdx.x;
    int node = idx / FV;
    int fo   = (idx % FV) * 4;
    if (node >= NN) return;
    unsigned short* p = c + (size_t)node * LD + fo;
    uint2 v = *(uint2*)p;
    float a0 = bfl(v.x), a1 = bfh(v.x), a2 = bfl(v.y), a3 = bfh(v.y);
    float4 sc = *(const float4*)(scale + fo);
    float4 sh = *(const float4*)(shift + fo);
    a0 = fmaf(a0, sc.x, sh.x);
    a1 = fmaf(a1, sc.y, sh.y);
    a2 = fmaf(a2, sc.z, sh.z);
    a3 = fmaf(a3, sc.w, sh.w);
    v.x = pack2(a0, a1); v.y = pack2(a2, a3);
    *(uint2*)p = v;
}

// ---------------- head GEMM via MFMA: out = Jh @ W_head + b ----------------
__global__ __launch_bounds__(256) void head_mfma_kernel(const unsigned short* __restrict__ Jh,
                                                        const unsigned short* __restrict__ Wb,
                                                        const float* __restrict__ b,
                                                        float* __restrict__ out) {
    int wave = threadIdx.x >> 6;
    int lane = threadIdx.x & 63;
    int tile = blockIdx.x * 4 + wave;
    if (tile >= NT) return;
    int m = lane & 15;
    int q = lane >> 4;
    const unsigned short* arow  = Jh + (size_t)(tile * 16 + m) * LD + q * 8;
    const unsigned short* bbase = Wb + (size_t)lane * 8;
    f32x4 acc0 = {0.f, 0.f, 0.f, 0.f};
    f32x4 acc1 = {0.f, 0.f, 0.f, 0.f};
    #pragma unroll 5
    for (int kb = 0; kb < 30; kb++) {
        bf16x8 a  = *(const bf16x8*)(arow + kb * 32);
        bf16x8 b0 = *(const bf16x8*)(bbase + (size_t)kb * 512);
        bf16x8 b1 = *(const bf16x8*)(bbase + (size_t)(30 + kb) * 512);
        acc0 = __builtin_amdgcn_mfma_f32_16x16x32_bf16(a, b0, acc0, 0, 0, 0);
        acc1 = __builtin_amdgcn_mfma_f32_16x16x32_bf16(a, b1, acc1, 0, 0, 0);
    }
    int col = m;
    float b0 = b[col], b1 = b[16 + col];
    #pragma unroll
    for (int r = 0; r < 4; r++) {
        float* op = out + (size_t)(tile * 16 + q * 4 + r) * 32 + col;
        op[0]  = acc0[r] + b0;
        op[16] = acc1[r] + b1;
    }
}

// ---------------- launch ----------------

extern "C" void kernel_launch(void* const* d_in, const int* in_sizes, int n_in,
                              void* d_out, int out_size, void* d_ws, size_t ws_size,
                              hipStream_t stream) {
    const float* x      = (const float*)d_in[0];
    const int*   e1_row = (const int*)d_in[1];
    const int*   e1_col = (const int*)d_in[2];
    const float* e1_val = (const float*)d_in[3];
    const int*   e2_row = (const int*)d_in[4];
    const int*   e2_col = (const int*)d_in[5];
    const float* e2_val = (const float*)d_in[6];
    const float* W_emb  = (const float*)d_in[7];
    const float* b_emb  = (const float*)d_in[8];
    const float* bn0_g  = (const float*)d_in[9];
    const float* bn0_b  = (const float*)d_in[10];
    const float* bn1_g  = (const float*)d_in[11];
    const float* bn1_b  = (const float*)d_in[12];
    const float* W_head = (const float*)d_in[13];
    const float* b_head = (const float*)d_in[14];
    float* out = (float*)d_out;

    char* ws = (char*)d_ws;
    auto alloc = [&](size_t bytes) -> char* {
        char* p = ws;
        ws += (bytes + 255) & ~(size_t)255;
        return p;
    };
    int*   rp1   = (int*)alloc((NN + 1) * 4);
    int*   cur1  = (int*)alloc(NN * 4);
    int*   rp2   = (int*)alloc((NN + 1) * 4);
    int*   cur2  = (int*)alloc(NN * 4);
    int*   cs1   = (int*)alloc(E1N * 4);
    float* vs1   = (float*)alloc(E1N * 4);
    int*   cs2   = (int*)alloc(E2N * 4);
    float* vs2   = (float*)alloc(E2N * 4);
    float* stats = (float*)alloc(1536 * 4);
    unsigned short* Wbh = (unsigned short*)alloc(3840 * 8 * 2);   // head: 2 ctiles x 30 kb x 64
    unsigned short* Wbe = (unsigned short*)alloc(2048 * 8 * 2);   // embed: 4 ctiles x 8 kb x 64
    unsigned short* Jh  = (unsigned short*)alloc((size_t)NN * LD * 2);

    float* sum0   = stats;        float* sq0    = stats + 128;
    float* sum1   = stats + 256;  float* sq1    = stats + 512;
    float* scale0 = stats + 768;  float* shift0 = stats + 896;
    float* scale1 = stats + 1024; float* shift1 = stats + 1280;

    const int EB = (E1N + E2N + 255) / 256;

    // CSR build + weight packs
    zero_kernel<<<(NN + 255) / 256, 256, 0, stream>>>(cur1, NN, cur2, NN, stats, 768);
    hist_kernel<<<EB, 256, 0, stream>>>(e1_row, e2_row, cur1, cur2);
    scan_kernel<<<2, 1024, 0, stream>>>(cur1, rp1, cur2, rp2);
    scatter_kernel<<<EB, 256, 0, stream>>>(e1_row, e1_col, e1_val, e2_row, e2_col, e2_val,
                                           cur1, cs1, vs1, cur2, cs2, vs2);
    packw_kernel<<<15, 256, 0, stream>>>(W_head, Wbh, 32, 30, 3840);
    packw_kernel<<<8, 256, 0, stream>>>(W_emb, Wbe, 64, 8, 2048);

    // embed -> Jh[:,0:64) (MFMA)
    embed_mfma_kernel<<<(NT + 3) / 4, 256, 0, stream>>>(x, Wbe, b_emb, Jh);

    // conv0 -> Jh[:,64:192), then BN
    spmm_dual_kernel<1><<<2 * RB, 256, 0, stream>>>(rp1, cs1, vs1, rp2, cs2, vs2, Jh, Jh + 64);
    bn_stats_kernel<128><<<512, 256, 0, stream>>>(Jh + 64, sum0, sq0);
    bn_finalize_kernel<<<1, 128, 0, stream>>>(sum0, sq0, bn0_g, bn0_b, scale0, shift0, 128);
    bn_apply_kernel<128><<<(NN * 32 + 255) / 256, 256, 0, stream>>>(Jh + 64, scale0, shift0);

    // conv1 -> Jh[:,192:448), then BN
    spmm_dual_kernel<2><<<2 * RB, 256, 0, stream>>>(rp1, cs1, vs1, rp2, cs2, vs2, Jh + 64, Jh + 192);
    bn_stats_kernel<256><<<512, 256, 0, stream>>>(Jh + 192, sum1, sq1);
    bn_finalize_kernel<<<1, 256, 0, stream>>>(sum1, sq1, bn1_g, bn1_b, scale1, shift1, 256);
    bn_apply_kernel<256><<<(NN * 64 + 255) / 256, 256, 0, stream>>>(Jh + 192, scale1, shift1);

    // conv2 -> Jh[:,448:960)
    spmm_dual_kernel<4><<<2 * RB, 256, 0, stream>>>(rp1, cs1, vs1, rp2, cs2, vs2, Jh + 192, Jh + 448);

    // head (MFMA)
    head_mfma_kernel<<<(NT + 3) / 4, 256, 0, stream>>>(Jh, Wbh, b_head, out);
}

// Round 6
// 814.272 us; speedup vs baseline: 2.3318x; 1.1359x over previous
//
#include <hip/hip_runtime.h>

// H2GCN forward, bf16 activations in fused Jh[N,960]:
//   cols [0,64)=h [64,192)=c0 [192,448)=c1 [448,960)=c2.
// conv0/conv1: pull-SPMM bf16 gather (8B/lane, multi-row waves), fp32 acc.
// conv2: pull-SPMM over fp8 e4m3 copy of BN'd c1 (half gather bytes).
// Embed + Head: MFMA 16x16x32 bf16, weights pre-packed to B-fragment layout.

#define NN  50000
#define E1N 800000
#define E2N 1600000
#define LD  960
#define NT  3125         // 16-node tiles

typedef short bf16x8 __attribute__((ext_vector_type(8)));
typedef float f32x4  __attribute__((ext_vector_type(4)));
typedef float f32x2  __attribute__((ext_vector_type(2)));

__device__ __forceinline__ float bfl(unsigned int w) { return __uint_as_float(w << 16); }
__device__ __forceinline__ float bfh(unsigned int w) { return __uint_as_float(w & 0xFFFF0000u); }
__device__ __forceinline__ float bf2f(unsigned short u) { return __uint_as_float(((unsigned int)u) << 16); }
__device__ __forceinline__ unsigned short f2bf(float f) {         // RNE
    unsigned int u = __float_as_uint(f);
    u += 0x7FFFu + ((u >> 16) & 1u);
    return (unsigned short)(u >> 16);
}
__device__ __forceinline__ unsigned int pack2(float a, float b) {
    return (unsigned int)f2bf(a) | ((unsigned int)f2bf(b) << 16);
}

// ---------------- setup kernels ----------------

__global__ __launch_bounds__(256) void zero_kernel(int* a, int na, int* b, int nb, float* c, int nc) {
    int i = blockIdx.x * 256 + threadIdx.x;
    if (i < na) a[i] = 0;
    if (i < nb) b[i] = 0;
    if (i < nc) c[i] = 0.f;
}

__global__ __launch_bounds__(256) void hist_kernel(const int* __restrict__ r1, const int* __restrict__ r2,
                                                   int* h1, int* h2) {
    int i = blockIdx.x * 256 + threadIdx.x;
    if (i < E1N) atomicAdd(&h1[r1[i]], 1);
    else if (i < E1N + E2N) atomicAdd(&h2[r2[i - E1N]], 1);
}

__global__ __launch_bounds__(1024) void scan_kernel(int* hist1, int* rp1, int* hist2, int* rp2) {
    int* hist = blockIdx.x ? hist2 : hist1;
    int* rp   = blockIdx.x ? rp2   : rp1;
    const int t = threadIdx.x;
    const int CH = 49;
    int base = t * CH;
    int lim = NN - base; if (lim > CH) lim = CH; if (lim < 0) lim = 0;
    int lsum = 0;
    for (int j = 0; j < lim; j++) lsum += hist[base + j];
    __shared__ int s[1024];
    s[t] = lsum;
    __syncthreads();
    for (int off = 1; off < 1024; off <<= 1) {
        int v = (t >= off) ? s[t - off] : 0;
        __syncthreads();
        s[t] += v;
        __syncthreads();
    }
    int run = s[t] - lsum;
    for (int j = 0; j < lim; j++) {
        int hv = hist[base + j];
        rp[base + j]   = run;
        hist[base + j] = run;
        run += hv;
    }
    if (t == 0) rp[NN] = s[1023];
}

__global__ __launch_bounds__(256) void scatter_kernel(
        const int* __restrict__ r1, const int* __restrict__ c1, const float* __restrict__ v1,
        const int* __restrict__ r2, const int* __restrict__ c2, const float* __restrict__ v2,
        int* cur1, int* cs1, float* vs1, int* cur2, int* cs2, float* vs2) {
    int i = blockIdx.x * 256 + threadIdx.x;
    if (i < E1N) {
        int r = r1[i];
        int idx = atomicAdd(&cur1[r], 1);
        cs1[idx] = c1[i]; vs1[idx] = v1[i];
    } else if (i < E1N + E2N) {
        int k = i - E1N;
        int r = r2[k];
        int idx = atomicAdd(&cur2[r], 1);
        cs2[idx] = c2[k]; vs2[idx] = v2[k];
    }
}

// ---------------- weight -> bf16 B-fragment pack ----------------
__global__ __launch_bounds__(256) void packw_kernel(const float* __restrict__ W, unsigned short* __restrict__ Wb,
                                                    int NC, int kbs, int total) {
    int i = blockIdx.x * 256 + threadIdx.x;
    if (i >= total) return;
    int lane  = i & 63;
    int kb    = (i >> 6) % kbs;
    int ctile = i / (kbs * 64);
    int n  = ctile * 16 + (lane & 15);
    int k0 = kb * 32 + (lane >> 4) * 8;
    unsigned short v[8];
    #pragma unroll
    for (int j = 0; j < 8; j++) v[j] = f2bf(W[(k0 + j) * NC + n]);
    *(uint4*)(Wb + (size_t)i * 8) = *(uint4*)v;
}

// ---------------- embed via MFMA ----------------
__global__ __launch_bounds__(256) void embed_mfma_kernel(const float* __restrict__ x,
                                                         const unsigned short* __restrict__ Wb,
                                                         const float* __restrict__ bias,
                                                         unsigned short* __restrict__ Jh) {
    int wave = threadIdx.x >> 6;
    int lane = threadIdx.x & 63;
    int tile = blockIdx.x * 4 + wave;
    if (tile >= NT) return;
    int m = lane & 15;
    int q = lane >> 4;
    const float* xr = x + (size_t)(tile * 16 + m) * 256 + q * 8;
    const unsigned short* bbase = Wb + (size_t)lane * 8;
    f32x4 acc[4];
    #pragma unroll
    for (int ct = 0; ct < 4; ct++) acc[ct] = (f32x4){0.f, 0.f, 0.f, 0.f};
    #pragma unroll
    for (int kb = 0; kb < 8; kb++) {
        float4 xa = *(const float4*)(xr + kb * 32);
        float4 xb = *(const float4*)(xr + kb * 32 + 4);
        unsigned short av[8];
        av[0] = f2bf(xa.x); av[1] = f2bf(xa.y); av[2] = f2bf(xa.z); av[3] = f2bf(xa.w);
        av[4] = f2bf(xb.x); av[5] = f2bf(xb.y); av[6] = f2bf(xb.z); av[7] = f2bf(xb.w);
        bf16x8 a = *(bf16x8*)av;
        #pragma unroll
        for (int ct = 0; ct < 4; ct++) {
            bf16x8 bfr = *(const bf16x8*)(bbase + (size_t)(ct * 8 + kb) * 512);
            acc[ct] = __builtin_amdgcn_mfma_f32_16x16x32_bf16(a, bfr, acc[ct], 0, 0, 0);
        }
    }
    #pragma unroll
    for (int ct = 0; ct < 4; ct++) {
        int col = ct * 16 + m;
        float bb = bias[col];
        #pragma unroll
        for (int r = 0; r < 4; r++) {
            float v = fmaxf(acc[ct][r] + bb, 0.f);
            Jh[(size_t)(tile * 16 + q * 4 + r) * LD + col] = f2bf(v);
        }
    }
}

// ---------------- pull SPMM, bf16 source, LPR lanes per row (4 feats/lane) ----------------
// ROWS = 64/LPR rows per wave; 4 waves/block; both graphs in one grid.
template <int LPR>
__global__ __launch_bounds__(256) void spmm_bf16_kernel(
        const int* __restrict__ rp1, const int* __restrict__ cs1, const float* __restrict__ vs1,
        const int* __restrict__ rp2, const int* __restrict__ cs2, const float* __restrict__ vs2,
        const unsigned short* __restrict__ src,   // Jh + src col offset, SRCF wide
        unsigned short* __restrict__ dst) {       // Jh + dst col offset (graph1 base)
    constexpr int ROWS = 64 / LPR;
    constexpr int SRCF = LPR * 4;
    constexpr int GB   = NN / (ROWS * 4);         // blocks per graph (exact)
    int g    = (blockIdx.x >= GB) ? 1 : 0;
    int bx   = blockIdx.x - g * GB;
    int wave = threadIdx.x >> 6;
    int lane = threadIdx.x & 63;
    int grp  = lane / LPR;
    int sub  = lane % LPR;
    int row  = (bx * 4 + wave) * ROWS + grp;
    const int*   rp = g ? rp2 : rp1;
    const int*   cs = g ? cs2 : cs1;
    const float* vs = g ? vs2 : vs1;
    int beg = rp[row], end = rp[row + 1];

    float acc[4] = {0.f, 0.f, 0.f, 0.f};
    const unsigned short* sbase = src + sub * 4;

    int j = beg;
    for (; j + 8 <= end; j += 8) {
        int   c[8]; float v[8];
        #pragma unroll
        for (int u = 0; u < 8; u++) { c[u] = cs[j + u]; v[u] = vs[j + u]; }
        uint2 s[8];
        #pragma unroll
        for (int u = 0; u < 8; u++) s[u] = *(const uint2*)(sbase + (size_t)c[u] * LD);
        #pragma unroll
        for (int u = 0; u < 8; u++) {
            acc[0]=fmaf(v[u],bfl(s[u].x),acc[0]); acc[1]=fmaf(v[u],bfh(s[u].x),acc[1]);
            acc[2]=fmaf(v[u],bfl(s[u].y),acc[2]); acc[3]=fmaf(v[u],bfh(s[u].y),acc[3]);
        }
    }
    for (; j < end; j++) {
        int c = cs[j]; float v = vs[j];
        uint2 s = *(const uint2*)(sbase + (size_t)c * LD);
        acc[0]=fmaf(v,bfl(s.x),acc[0]); acc[1]=fmaf(v,bfh(s.x),acc[1]);
        acc[2]=fmaf(v,bfl(s.y),acc[2]); acc[3]=fmaf(v,bfh(s.y),acc[3]);
    }

    unsigned short* dp = dst + (size_t)row * LD + g * SRCF + sub * 4;
    uint2 o; o.x = pack2(acc[0], acc[1]); o.y = pack2(acc[2], acc[3]);
    *(uint2*)dp = o;
}

// ---------------- pull SPMM, fp8 e4m3 source (conv2): 64 lanes x 4 fp8 ----------------
__global__ __launch_bounds__(256) void spmm_fp8_kernel(
        const int* __restrict__ rp1, const int* __restrict__ cs1, const float* __restrict__ vs1,
        const int* __restrict__ rp2, const int* __restrict__ cs2, const float* __restrict__ vs2,
        const unsigned char* __restrict__ src8,   // C1f8[N,256] e4m3
        unsigned short* __restrict__ dst) {       // Jh + 448
    constexpr int GB = NN / 4;                    // 12500 blocks per graph
    int g    = (blockIdx.x >= GB) ? 1 : 0;
    int bx   = blockIdx.x - g * GB;
    int wave = threadIdx.x >> 6;
    int lane = threadIdx.x & 63;
    int row  = bx * 4 + wave;
    const int*   rp = g ? rp2 : rp1;
    const int*   cs = g ? cs2 : cs1;
    const float* vs = g ? vs2 : vs1;
    int beg = rp[row], end = rp[row + 1];

    float acc[4] = {0.f, 0.f, 0.f, 0.f};
    const unsigned char* sbase = src8 + lane * 4;

    int j = beg;
    for (; j + 8 <= end; j += 8) {
        int   c[8]; float v[8];
        #pragma unroll
        for (int u = 0; u < 8; u++) { c[u] = cs[j + u]; v[u] = vs[j + u]; }
        unsigned int s[8];
        #pragma unroll
        for (int u = 0; u < 8; u++) s[u] = *(const unsigned int*)(sbase + (size_t)c[u] * 256);
        #pragma unroll
        for (int u = 0; u < 8; u++) {
            f32x2 lo = __builtin_amdgcn_cvt_pk_f32_fp8(s[u], false);
            f32x2 hi = __builtin_amdgcn_cvt_pk_f32_fp8(s[u], true);
            acc[0]=fmaf(v[u],lo[0],acc[0]); acc[1]=fmaf(v[u],lo[1],acc[1]);
            acc[2]=fmaf(v[u],hi[0],acc[2]); acc[3]=fmaf(v[u],hi[1],acc[3]);
        }
    }
    for (; j < end; j++) {
        int c = cs[j]; float v = vs[j];
        unsigned int s = *(const unsigned int*)(sbase + (size_t)c * 256);
        f32x2 lo = __builtin_amdgcn_cvt_pk_f32_fp8(s, false);
        f32x2 hi = __builtin_amdgcn_cvt_pk_f32_fp8(s, true);
        acc[0]=fmaf(v,lo[0],acc[0]); acc[1]=fmaf(v,lo[1],acc[1]);
        acc[2]=fmaf(v,hi[0],acc[2]); acc[3]=fmaf(v,hi[1],acc[3]);
    }

    unsigned short* dp = dst + (size_t)row * LD + g * 256 + lane * 4;
    uint2 o; o.x = pack2(acc[0], acc[1]); o.y = pack2(acc[2], acc[3]);
    *(uint2*)dp = o;
}

// ---------------- BN stats / finalize / apply ----------------
template <int F>
__global__ __launch_bounds__(256) void bn_stats_kernel(const unsigned short* __restrict__ c,
                                                       float* sum, float* sumsq) {
    constexpr int SL = 256 / F;
    int f  = threadIdx.x % F;
    int sl = threadIdx.x / F;
    float s = 0.f, ss = 0.f;
    for (int r = blockIdx.x * SL + sl; r < NN; r += gridDim.x * SL) {
        float v = bf2f(c[(size_t)r * LD + f]);
        s += v; ss += v * v;
    }
    __shared__ float ls[256], lss[256];
    ls[threadIdx.x] = s; lss[threadIdx.x] = ss;
    __syncthreads();
    if (sl == 0) {
        #pragma unroll
        for (int u = 1; u < SL; u++) { s += ls[f + u * F]; ss += lss[f + u * F]; }
        atomicAdd(&sum[f], s);
        atomicAdd(&sumsq[f], ss);
    }
}

__global__ void bn_finalize_kernel(const float* sum, const float* sumsq, const float* __restrict__ gamma,
                                   const float* __restrict__ beta, float* scale, float* shift, int F) {
    int f = blockIdx.x * blockDim.x + threadIdx.x;
    if (f >= F) return;
    float m   = sum[f] * (1.0f / NN);
    float var = sumsq[f] * (1.0f / NN) - m * m;
    float sc  = gamma[f] * rsqrtf(var + 1e-5f);
    scale[f] = sc;
    shift[f] = beta[f] - m * sc;
}

// bf16 in-place BN apply (c0, F=128)
template <int F>
__global__ __launch_bounds__(256) void bn_apply_kernel(unsigned short* __restrict__ c,
                                                       const float* __restrict__ scale,
                                                       const float* __restrict__ shift) {
    constexpr int FV = F / 4;
    int idx  = blockIdx.x * 256 + threadIdx.x;
    int node = idx / FV;
    int fo   = (idx % FV) * 4;
    if (node >= NN) return;
    unsigned short* p = c + (size_t)node * LD + fo;
    uint2 v = *(uint2*)p;
    float a0 = bfl(v.x), a1 = bfh(v.x), a2 = bfl(v.y), a3 = bfh(v.y);
    float4 sc = *(const float4*)(scale + fo);
    float4 sh = *(const float4*)(shift + fo);
    a0 = fmaf(a0, sc.x, sh.x);
    a1 = fmaf(a1, sc.y, sh.y);
    a2 = fmaf(a2, sc.z, sh.z);
    a3 = fmaf(a3, sc.w, sh.w);
    v.x = pack2(a0, a1); v.y = pack2(a2, a3);
    *(uint2*)p = v;
}

// BN apply on c1 (F=256): write bf16 back to Jh AND e4m3 copy for conv2's gather
__global__ __launch_bounds__(256) void bn_apply_fp8_kernel(unsigned short* __restrict__ c,
                                                           unsigned char* __restrict__ c8,
                                                           const float* __restrict__ scale,
                                                           const float* __restrict__ shift) {
    int idx  = blockIdx.x * 256 + threadIdx.x;
    int node = idx >> 6;                // 64 groups of 4 feats
    int fo   = (idx & 63) * 4;
    if (node >= NN) return;
    unsigned short* p = c + (size_t)node * LD + fo;
    uint2 v = *(uint2*)p;
    float a0 = bfl(v.x), a1 = bfh(v.x), a2 = bfl(v.y), a3 = bfh(v.y);
    float4 sc = *(const float4*)(scale + fo);
    float4 sh = *(const float4*)(shift + fo);
    a0 = fmaf(a0, sc.x, sh.x);
    a1 = fmaf(a1, sc.y, sh.y);
    a2 = fmaf(a2, sc.z, sh.z);
    a3 = fmaf(a3, sc.w, sh.w);
    v.x = pack2(a0, a1); v.y = pack2(a2, a3);
    *(uint2*)p = v;
    int w = __builtin_amdgcn_cvt_pk_fp8_f32(a0, a1, 0, false);
    w     = __builtin_amdgcn_cvt_pk_fp8_f32(a2, a3, w, true);
    *(unsigned int*)(c8 + (size_t)node * 256 + fo) = (unsigned int)w;
}

// ---------------- head GEMM via MFMA ----------------
__global__ __launch_bounds__(256) void head_mfma_kernel(const unsigned short* __restrict__ Jh,
                                                        const unsigned short* __restrict__ Wb,
                                                        const float* __restrict__ b,
                                                        float* __restrict__ out) {
    int wave = threadIdx.x >> 6;
    int lane = threadIdx.x & 63;
    int tile = blockIdx.x * 4 + wave;
    if (tile >= NT) return;
    int m = lane & 15;
    int q = lane >> 4;
    const unsigned short* arow  = Jh + (size_t)(tile * 16 + m) * LD + q * 8;
    const unsigned short* bbase = Wb + (size_t)lane * 8;
    f32x4 acc0 = {0.f, 0.f, 0.f, 0.f};
    f32x4 acc1 = {0.f, 0.f, 0.f, 0.f};
    #pragma unroll 5
    for (int kb = 0; kb < 30; kb++) {
        bf16x8 a  = *(const bf16x8*)(arow + kb * 32);
        bf16x8 b0 = *(const bf16x8*)(bbase + (size_t)kb * 512);
        bf16x8 b1 = *(const bf16x8*)(bbase + (size_t)(30 + kb) * 512);
        acc0 = __builtin_amdgcn_mfma_f32_16x16x32_bf16(a, b0, acc0, 0, 0, 0);
        acc1 = __builtin_amdgcn_mfma_f32_16x16x32_bf16(a, b1, acc1, 0, 0, 0);
    }
    int col = m;
    float b0 = b[col], b1 = b[16 + col];
    #pragma unroll
    for (int r = 0; r < 4; r++) {
        float* op = out + (size_t)(tile * 16 + q * 4 + r) * 32 + col;
        op[0]  = acc0[r] + b0;
        op[16] = acc1[r] + b1;
    }
}

// ---------------- launch ----------------

extern "C" void kernel_launch(void* const* d_in, const int* in_sizes, int n_in,
                              void* d_out, int out_size, void* d_ws, size_t ws_size,
                              hipStream_t stream) {
    const float* x      = (const float*)d_in[0];
    const int*   e1_row = (const int*)d_in[1];
    const int*   e1_col = (const int*)d_in[2];
    const float* e1_val = (const float*)d_in[3];
    const int*   e2_row = (const int*)d_in[4];
    const int*   e2_col = (const int*)d_in[5];
    const float* e2_val = (const float*)d_in[6];
    const float* W_emb  = (const float*)d_in[7];
    const float* b_emb  = (const float*)d_in[8];
    const float* bn0_g  = (const float*)d_in[9];
    const float* bn0_b  = (const float*)d_in[10];
    const float* bn1_g  = (const float*)d_in[11];
    const float* bn1_b  = (const float*)d_in[12];
    const float* W_head = (const float*)d_in[13];
    const float* b_head = (const float*)d_in[14];
    float* out = (float*)d_out;

    char* ws = (char*)d_ws;
    auto alloc = [&](size_t bytes) -> char* {
        char* p = ws;
        ws += (bytes + 255) & ~(size_t)255;
        return p;
    };
    int*   rp1   = (int*)alloc((NN + 1) * 4);
    int*   cur1  = (int*)alloc(NN * 4);
    int*   rp2   = (int*)alloc((NN + 1) * 4);
    int*   cur2  = (int*)alloc(NN * 4);
    int*   cs1   = (int*)alloc(E1N * 4);
    float* vs1   = (float*)alloc(E1N * 4);
    int*   cs2   = (int*)alloc(E2N * 4);
    float* vs2   = (float*)alloc(E2N * 4);
    float* stats = (float*)alloc(1536 * 4);
    unsigned short* Wbh  = (unsigned short*)alloc(3840 * 8 * 2);
    unsigned short* Wbe  = (unsigned short*)alloc(2048 * 8 * 2);
    unsigned char*  C1f8 = (unsigned char*)alloc((size_t)NN * 256);
    unsigned short* Jh   = (unsigned short*)alloc((size_t)NN * LD * 2);

    float* sum0   = stats;        float* sq0    = stats + 128;
    float* sum1   = stats + 256;  float* sq1    = stats + 512;
    float* scale0 = stats + 768;  float* shift0 = stats + 896;
    float* scale1 = stats + 1024; float* shift1 = stats + 1280;

    const int EB = (E1N + E2N + 255) / 256;

    // CSR build + weight packs
    zero_kernel<<<(NN + 255) / 256, 256, 0, stream>>>(cur1, NN, cur2, NN, stats, 768);
    hist_kernel<<<EB, 256, 0, stream>>>(e1_row, e2_row, cur1, cur2);
    scan_kernel<<<2, 1024, 0, stream>>>(cur1, rp1, cur2, rp2);
    scatter_kernel<<<EB, 256, 0, stream>>>(e1_row, e1_col, e1_val, e2_row, e2_col, e2_val,
                                           cur1, cs1, vs1, cur2, cs2, vs2);
    packw_kernel<<<15, 256, 0, stream>>>(W_head, Wbh, 32, 30, 3840);
    packw_kernel<<<8, 256, 0, stream>>>(W_emb, Wbe, 64, 8, 2048);

    // embed -> Jh[:,0:64) (MFMA)
    embed_mfma_kernel<<<(NT + 3) / 4, 256, 0, stream>>>(x, Wbe, b_emb, Jh);

    // conv0 -> Jh[:,64:192), then BN (src h: 64 wide, 16 lanes/row, 4 rows/wave)
    spmm_bf16_kernel<16><<<2 * (NN / 16), 256, 0, stream>>>(rp1, cs1, vs1, rp2, cs2, vs2, Jh, Jh + 64);
    bn_stats_kernel<128><<<512, 256, 0, stream>>>(Jh + 64, sum0, sq0);
    bn_finalize_kernel<<<1, 128, 0, stream>>>(sum0, sq0, bn0_g, bn0_b, scale0, shift0, 128);
    bn_apply_kernel<128><<<(NN * 32 + 255) / 256, 256, 0, stream>>>(Jh + 64, scale0, shift0);

    // conv1 -> Jh[:,192:448), then BN + fp8 copy (src c0': 128 wide, 32 lanes/row, 2 rows/wave)
    spmm_bf16_kernel<32><<<2 * (NN / 8), 256, 0, stream>>>(rp1, cs1, vs1, rp2, cs2, vs2, Jh + 64, Jh + 192);
    bn_stats_kernel<256><<<512, 256, 0, stream>>>(Jh + 192, sum1, sq1);
    bn_finalize_kernel<<<1, 256, 0, stream>>>(sum1, sq1, bn1_g, bn1_b, scale1, shift1, 256);
    bn_apply_fp8_kernel<<<(NN * 64 + 255) / 256, 256, 0, stream>>>(Jh + 192, C1f8, scale1, shift1);

    // conv2 -> Jh[:,448:960) (src C1f8: 256 fp8 wide)
    spmm_fp8_kernel<<<2 * (NN / 4), 256, 0, stream>>>(rp1, cs1, vs1, rp2, cs2, vs2, C1f8, Jh + 448);

    // head (MFMA)
    head_mfma_kernel<<<(NT + 3) / 4, 256, 0, stream>>>(Jh, Wbh, b_head, out);
}